// Round 15
// baseline (772.938 us; speedup 1.0000x reference)
//
#include <hip/hip_runtime.h>
#include <hip/hip_bf16.h>

#define NTOK 2048

typedef __attribute__((ext_vector_type(8))) short short8_t;
typedef __attribute__((ext_vector_type(4))) float f32x4;

__device__ __forceinline__ float bu2f(unsigned short u) {
  unsigned int x = ((unsigned int)u) << 16; float f; __builtin_memcpy(&f, &x, 4); return f;
}
__device__ __forceinline__ unsigned short f2bu(float f) {
  __hip_bfloat16 h = __float2bfloat16(f);
  unsigned short u; __builtin_memcpy(&u, &h, 2); return u;
}
__device__ __forceinline__ float sigm(float x) { return 1.0f / (1.0f + __expf(-x)); }
__device__ __forceinline__ uint4 pack8(const float* v) {
  unsigned short u[8];
#pragma unroll
  for (int i = 0; i < 8; ++i) u[i] = f2bu(v[i]);
  uint4 r; __builtin_memcpy(&r, u, 16); return r;
}
__device__ __forceinline__ short8_t pk8s(const float* v) {
  unsigned short u[8];
#pragma unroll
  for (int i = 0; i < 8; ++i) u[i] = f2bu(v[i]);
  short8_t r; __builtin_memcpy(&r, u, 16); return r;
}

__device__ __forceinline__ short8_t wfrag(const float* __restrict__ W,
                                          const float* __restrict__ lns,
                                          int ko, int n) {
  float v[8];
#pragma unroll
  for (int i = 0; i < 8; ++i) v[i] = W[(size_t)(ko + i) * 128 + n];
  if (lns) {
    float4 l0 = *(const float4*)(lns + ko);
    float4 l1 = *(const float4*)(lns + ko + 4);
    v[0] *= l0.x; v[1] *= l0.y; v[2] *= l0.z; v[3] *= l0.w;
    v[4] *= l1.x; v[5] *= l1.y; v[6] *= l1.z; v[7] *= l1.w;
  }
  return pk8s(v);
}

__device__ __forceinline__ void gemm_dw(const unsigned short* a_lds,
                                        const float* __restrict__ W,
                                        const float* __restrict__ lns,
                                        int lm, int kg, int wv, f32x4 acc[2][2]) {
  const int xa = (lm & 7) << 3;
#pragma unroll
  for (int ks = 0; ks < 4; ++ks) {
    const int ko = ks * 32 + kg * 8;
    short8_t av[2], bv[2];
#pragma unroll
    for (int mi = 0; mi < 2; ++mi)
      av[mi] = *(const short8_t*)&a_lds[(mi * 16 + lm) * 128 + (ko ^ xa)];
#pragma unroll
    for (int ni = 0; ni < 2; ++ni)
      bv[ni] = wfrag(W, lns, ko, (wv * 2 + ni) * 16 + lm);
#pragma unroll
    for (int mi = 0; mi < 2; ++mi)
#pragma unroll
      for (int ni = 0; ni < 2; ++ni)
        acc[mi][ni] = __builtin_amdgcn_mfma_f32_16x16x32_bf16(av[mi], bv[ni], acc[mi][ni], 0, 0, 0);
  }
}

// ------------------------------------------------------------------
// N1 (DIAGNOSTIC reps): proj blocks [0,320) first; bias blocks [320,1344).
// ------------------------------------------------------------------
__global__ __launch_bounds__(256) void bias_proj_kernel(
    const float* __restrict__ act, const float* __restrict__ cond,
    const float* __restrict__ lns_q, const float* __restrict__ lns_k,
    const float* __restrict__ WgQ, const float* __restrict__ WsQ,
    const float* __restrict__ WgK, const float* __restrict__ WsK,
    const float* __restrict__ Wq, const float* __restrict__ Wk,
    const float* __restrict__ Wv, const float* __restrict__ Wg,
    const float* __restrict__ Wgs,
    const float* __restrict__ bgate_q, const float* __restrict__ bgate_k,
    const float* __restrict__ bq, const float* __restrict__ bgs,
    const float* __restrict__ pair, const float* __restrict__ lnz_w,
    const float* __restrict__ Wb,
    unsigned short* __restrict__ q_b, unsigned short* __restrict__ k_b,
    unsigned short* __restrict__ vt_b, unsigned short* __restrict__ gsig_b,
    unsigned short* __restrict__ gs_b, unsigned short* __restrict__ bias_h,
    int reps)
{
  __shared__ unsigned short a_lds[32 * 128];
  __shared__ unsigned short xn_lds[32 * 136];
  __shared__ unsigned short a2_lds[32 * 128];
  __shared__ float lw[16];
  __shared__ float wbz[16][4];
  const int tid = threadIdx.x;
  const int bid = blockIdx.x;

  for (int rep = 0; rep < reps; ++rep) {
    asm volatile("" ::: "memory");
    if (bid >= 320) {
      // ---- windowed pair bias ----
      if (tid < 16) lw[tid] = lnz_w[tid];
      if (tid < 64) wbz[tid >> 2][tid & 3] = Wb[tid];
      __syncthreads();
      const int idx = (bid - 320) * 256 + tid;
      const int i = idx >> 7, jw = idx & 127;
      const int j = ((i >> 5) << 5) - 48 + jw;
      float bo[4] = {-1e9f, -1e9f, -1e9f, -1e9f};
      if (j >= 0 && j < NTOK) {
        const float4* p = (const float4*)(pair + ((size_t)i * NTOK + j) * 16);
        float4 z0 = p[0], z1 = p[1], z2 = p[2], z3 = p[3];
        float z[16] = {z0.x, z0.y, z0.z, z0.w, z1.x, z1.y, z1.z, z1.w,
                       z2.x, z2.y, z2.z, z2.w, z3.x, z3.y, z3.z, z3.w};
        float s = 0.f, ss = 0.f;
#pragma unroll
        for (int c = 0; c < 16; ++c) { s += z[c]; ss += z[c]*z[c]; }
        const float m = s * (1.f/16.f), v = ss * (1.f/16.f) - m*m;
        const float r = rsqrtf(v + 1e-5f);
        bo[0] = bo[1] = bo[2] = bo[3] = 0.f;
#pragma unroll
        for (int c = 0; c < 16; ++c) {
          const float zn = (z[c] - m) * r * lw[c];
          bo[0] += zn * wbz[c][0]; bo[1] += zn * wbz[c][1];
          bo[2] += zn * wbz[c][2]; bo[3] += zn * wbz[c][3];
        }
      }
#pragma unroll
      for (int h = 0; h < 4; ++h)
        bias_h[(size_t)h * (NTOK * 128) + idx] = f2bu(bo[h]);
    } else {
      // ---- self-contained projection ----
      const int br = bid / 64;
      const int rt = bid % 64;
      const int row0 = rt * 32;
      const int l = tid & 63, wv = tid >> 6;
      const int lm = l & 15, kg = l >> 4;
      { // LN stage
        const int r = tid >> 3;
        const int c0 = (tid & 7) << 4;
        float xv[16], cv[16];
        const float4* ap = (const float4*)(act + (size_t)(row0 + r) * 128 + c0);
        const float4* cp = (const float4*)(cond + (size_t)(row0 + r) * 128 + c0);
#pragma unroll
        for (int i = 0; i < 4; ++i) {
          float4 a4 = ap[i], b4 = cp[i];
          xv[4*i+0]=a4.x; xv[4*i+1]=a4.y; xv[4*i+2]=a4.z; xv[4*i+3]=a4.w;
          cv[4*i+0]=b4.x; cv[4*i+1]=b4.y; cv[4*i+2]=b4.z; cv[4*i+3]=b4.w;
        }
        float sx=0.f, sxx=0.f, sc=0.f, scc=0.f;
#pragma unroll
        for (int i = 0; i < 16; ++i) { sx+=xv[i]; sxx+=xv[i]*xv[i]; sc+=cv[i]; scc+=cv[i]*cv[i]; }
#pragma unroll
        for (int m = 1; m < 8; m <<= 1) {
          sx += __shfl_xor(sx, m); sxx += __shfl_xor(sxx, m);
          sc += __shfl_xor(sc, m); scc += __shfl_xor(scc, m);
        }
        const float mx = sx * (1.f/128.f), vx = sxx*(1.f/128.f) - mx*mx;
        const float mc = sc * (1.f/128.f), vc = scc*(1.f/128.f) - mc*mc;
        const float rx = rsqrtf(vx + 1e-5f), rc = rsqrtf(vc + 1e-5f);
        float xo[16], so[16];
#pragma unroll
        for (int i = 0; i < 16; ++i) { xo[i] = (xv[i]-mx)*rx; so[i] = (cv[i]-mc)*rc; }
        const int x = (r & 7) << 3;
        if (br == 4) {
          *(uint4*)&a_lds[r * 128 + (c0 ^ x)] = pack8(cv);
          *(uint4*)&a_lds[r * 128 + ((c0 + 8) ^ x)] = pack8(cv + 8);
        } else {
          *(uint4*)&a_lds[r * 128 + (c0 ^ x)] = pack8(so);
          *(uint4*)&a_lds[r * 128 + ((c0 + 8) ^ x)] = pack8(so + 8);
          *(uint4*)&xn_lds[r * 136 + c0] = pack8(xo);
          *(uint4*)&xn_lds[r * 136 + c0 + 8] = pack8(xo + 8);
        }
      }
      __syncthreads();

      if (br == 4) {
        f32x4 acc[2][2] = {};
        gemm_dw(a_lds, Wgs, nullptr, lm, kg, wv, acc);
        float bgv[2];
#pragma unroll
        for (int ni = 0; ni < 2; ++ni) bgv[ni] = bgs[(wv * 2 + ni) * 16 + lm];
#pragma unroll
        for (int mi = 0; mi < 2; ++mi)
#pragma unroll
          for (int ni = 0; ni < 2; ++ni)
#pragma unroll
            for (int r = 0; r < 4; ++r) {
              const int rl = mi * 16 + kg * 4 + r;
              const int n = (wv * 2 + ni) * 16 + lm;
              gs_b[(size_t)(row0 + rl) * 128 + n] = f2bu(sigm(acc[mi][ni][r] + bgv[ni]));
            }
      } else {
        const bool useq = (br < 2);
        const float* Wgt = useq ? WgQ : WgK;
        const float* Wsk = useq ? WsQ : WsK;
        const float* lns = useq ? lns_q : lns_k;
        const float* bg  = useq ? bgate_q : bgate_k;
        f32x4 ag[2][2] = {}, as2[2][2] = {};
        gemm_dw(a_lds, Wgt, lns, lm, kg, wv, ag);
        gemm_dw(a_lds, Wsk, lns, lm, kg, wv, as2);
        {
          float bgv[2];
#pragma unroll
          for (int ni = 0; ni < 2; ++ni) bgv[ni] = bg[(wv * 2 + ni) * 16 + lm];
#pragma unroll
          for (int mi = 0; mi < 2; ++mi)
#pragma unroll
            for (int ni = 0; ni < 2; ++ni)
#pragma unroll
              for (int r = 0; r < 4; ++r) {
                const int rl = mi * 16 + kg * 4 + r;
                const int n = (wv * 2 + ni) * 16 + lm;
                const float gate = sigm(ag[mi][ni][r] + bgv[ni]);
                const float a = gate * bu2f(xn_lds[rl * 136 + n]) + as2[mi][ni][r];
                a2_lds[rl * 128 + (n ^ ((rl & 7) << 3))] = f2bu(a);
              }
        }
        __syncthreads();
        const float* Wout = (br == 0) ? Wq : (br == 1) ? Wg : (br == 2) ? Wk : Wv;
        f32x4 ao[2][2] = {};
        gemm_dw(a2_lds, Wout, nullptr, lm, kg, wv, ao);
        if (br == 3) {
#pragma unroll
          for (int mi = 0; mi < 2; ++mi)
#pragma unroll
            for (int ni = 0; ni < 2; ++ni) {
              const int n = (wv * 2 + ni) * 16 + lm;
              const int tok0 = row0 + mi * 16 + kg * 4;
              ushort4 o;
              o.x = f2bu(ao[mi][ni][0]); o.y = f2bu(ao[mi][ni][1]);
              o.z = f2bu(ao[mi][ni][2]); o.w = f2bu(ao[mi][ni][3]);
              *(ushort4*)(vt_b + (size_t)n * NTOK + tok0) = o;
            }
        } else {
          const float scale = 0.17677669529663687f;
          float bqv[2] = {0.f, 0.f};
          if (br == 0) {
#pragma unroll
            for (int ni = 0; ni < 2; ++ni) bqv[ni] = bq[(wv * 2 + ni) * 16 + lm];
          }
          unsigned short* dst = (br == 0) ? q_b : (br == 1) ? gsig_b : k_b;
#pragma unroll
          for (int mi = 0; mi < 2; ++mi)
#pragma unroll
            for (int ni = 0; ni < 2; ++ni)
#pragma unroll
              for (int r = 0; r < 4; ++r) {
                const int rl = mi * 16 + kg * 4 + r;
                const int n = (wv * 2 + ni) * 16 + lm;
                float v = ao[mi][ni][r];
                if (br == 0) v = (v + bqv[ni]) * scale;
                else if (br == 1) v = sigm(v);
                dst[(size_t)(row0 + rl) * 128 + n] = f2bu(v);
              }
        }
      }
    }
    __syncthreads();
  }
}

// ------------------------------------------------------------------
// N2 (DIAGNOSTIC reps): attention per (qblock, head).
// ------------------------------------------------------------------
__global__ __launch_bounds__(256) void attn_kernel(
    const unsigned short* __restrict__ q_b, const unsigned short* __restrict__ k_b,
    const unsigned short* __restrict__ vt_b, const unsigned short* __restrict__ gsig_b,
    const unsigned short* __restrict__ bias_h, unsigned short* __restrict__ o_b,
    int reps)
{
  __shared__ unsigned short k_lds[128 * 64];
  __shared__ unsigned short vt[32 * 128];
  __shared__ unsigned short p_lds[32 * 128];
  __shared__ unsigned short q_lds[32 * 64];
  __shared__ unsigned short bias_lds[32 * 136];
  __shared__ float mxlds[4][32];
  __shared__ float smlds[4][32];
  __shared__ f32x4 op[16][64];
  const int tid = threadIdx.x;
  const int h = blockIdx.x & 3, b = blockIdx.x >> 2;
  const int j0 = b * 32 - 48;
  const int l = tid & 63, wv = tid >> 6;
  const int lm = l & 15, kg = l >> 4;

  for (int rep = 0; rep < reps; ++rep) {
    asm volatile("" ::: "memory");
    { // Q stage
      const int r = tid >> 3, c0 = (tid & 7) << 2;
      ushort4 v = *(const ushort4*)(q_b + (size_t)(b * 32 + r) * 128 + h * 32 + c0);
      *(ushort4*)&q_lds[r * 64 + (c0 ^ ((r & 7) << 3))] = v;
    }
    { // bias stage
      const int r = tid >> 3, c0 = (tid & 7) << 4;
      const uint4* g = (const uint4*)(bias_h + (size_t)h * (NTOK * 128) + (size_t)(b * 32 + r) * 128 + c0);
      uint4 v0 = g[0], v1 = g[1];
      *(uint4*)&bias_lds[r * 136 + c0] = v0;
      *(uint4*)&bias_lds[r * 136 + c0 + 8] = v1;
    }
    { // K stage
      const int jw = tid >> 1, cb = (tid & 1) << 4;
      const int j = j0 + jw;
      uint4 kv0 = {0,0,0,0}, kv1 = {0,0,0,0};
      if (j >= 0 && j < NTOK) {
        const uint4* gk = (const uint4*)(k_b + (size_t)j * 128 + h * 32 + cb);
        kv0 = gk[0]; kv1 = gk[1];
      }
      const int xk = (jw & 7) << 3;
      *(uint4*)&k_lds[jw * 64 + (cb ^ xk)] = kv0;
      *(uint4*)&k_lds[jw * 64 + ((cb + 8) ^ xk)] = kv1;
    }
    { // V stage from vt_b
      const int c = tid >> 3, koff = (tid & 7) << 4;
      const int j = j0 + koff;
      uint4 v0 = {0,0,0,0}, v1 = {0,0,0,0};
      if (j >= 0 && j + 15 < NTOK) {
        const uint4* gv = (const uint4*)(vt_b + (size_t)(h * 32 + c) * NTOK + j);
        v0 = gv[0]; v1 = gv[1];
      }
      const int xc = (c & 7) << 3;
      *(uint4*)&vt[c * 128 + (koff ^ xc)] = v0;
      *(uint4*)&vt[c * 128 + ((koff + 8) ^ xc)] = v1;
    }
    __syncthreads();

    f32x4 sc[2][2] = {};
    {
      const int xa = (lm & 7) << 3;
      short8_t aq[2], bk[2];
#pragma unroll
      for (int mi = 0; mi < 2; ++mi)
        aq[mi] = *(const short8_t*)&q_lds[(mi * 16 + lm) * 64 + ((kg * 8) ^ xa)];
#pragma unroll
      for (int ni = 0; ni < 2; ++ni) {
        const int key = (wv * 2 + ni) * 16 + lm;
        bk[ni] = *(const short8_t*)&k_lds[key * 64 + ((kg * 8) ^ ((key & 7) << 3))];
      }
#pragma unroll
      for (int mi = 0; mi < 2; ++mi)
#pragma unroll
        for (int ni = 0; ni < 2; ++ni)
          sc[mi][ni] = __builtin_amdgcn_mfma_f32_16x16x32_bf16(aq[mi], bk[ni], sc[mi][ni], 0, 0, 0);
    }
    float sv[2][2][4];
#pragma unroll
    for (int mi = 0; mi < 2; ++mi)
#pragma unroll
      for (int ni = 0; ni < 2; ++ni)
#pragma unroll
        for (int r = 0; r < 4; ++r) {
          const int q = mi * 16 + kg * 4 + r;
          const int key = (wv * 2 + ni) * 16 + lm;
          sv[mi][ni][r] = sc[mi][ni][r] + bu2f(bias_lds[q * 136 + key]);
        }
#pragma unroll
    for (int mi = 0; mi < 2; ++mi)
#pragma unroll
      for (int r = 0; r < 4; ++r) {
        float m0 = fmaxf(sv[mi][0][r], sv[mi][1][r]);
#pragma unroll
        for (int msk = 1; msk < 16; msk <<= 1) m0 = fmaxf(m0, __shfl_xor(m0, msk));
        if (lm == 0) mxlds[wv][mi * 16 + kg * 4 + r] = m0;
      }
    __syncthreads();
#pragma unroll
    for (int mi = 0; mi < 2; ++mi)
#pragma unroll
      for (int r = 0; r < 4; ++r) {
        const int q = mi * 16 + kg * 4 + r;
        const float m = fmaxf(fmaxf(mxlds[0][q], mxlds[1][q]), fmaxf(mxlds[2][q], mxlds[3][q]));
        float s = 0.f;
#pragma unroll
        for (int ni = 0; ni < 2; ++ni) {
          const float e = __expf(sv[mi][ni][r] - m);
          const int key = (wv * 2 + ni) * 16 + lm;
          p_lds[q * 128 + ((key & 7) | ((key & 120) ^ ((q & 7) << 3)))] = f2bu(e);
          s += e;
        }
#pragma unroll
        for (int msk = 1; msk < 16; msk <<= 1) s += __shfl_xor(s, msk);
        if (lm == 0) smlds[wv][q] = s;
      }
    f32x4 oacc[2][2] = {};
    {
      const int key0 = wv * 32 + kg * 8;
      short8_t pa[2], vbf[2];
#pragma unroll
      for (int mi = 0; mi < 2; ++mi) {
        const int q = mi * 16 + lm;
        pa[mi] = *(const short8_t*)&p_lds[q * 128 + (key0 ^ ((q & 7) << 3))];
      }
#pragma unroll
      for (int ct = 0; ct < 2; ++ct) {
        const int c = ct * 16 + lm;
        vbf[ct] = *(const short8_t*)&vt[c * 128 + (key0 ^ ((c & 7) << 3))];
      }
#pragma unroll
      for (int mi = 0; mi < 2; ++mi)
#pragma unroll
        for (int ct = 0; ct < 2; ++ct)
          oacc[mi][ct] = __builtin_amdgcn_mfma_f32_16x16x32_bf16(pa[mi], vbf[ct], oacc[mi][ct], 0, 0, 0);
    }
#pragma unroll
    for (int mi = 0; mi < 2; ++mi)
#pragma unroll
      for (int ct = 0; ct < 2; ++ct)
        op[wv * 4 + mi * 2 + ct][l] = oacc[mi][ct];
    __syncthreads();
    {
      const int q = tid >> 3, c0 = (tid & 7) << 2;
      const int mt = q >> 4, g = (q >> 2) & 3, r = q & 3;
      const float tot = smlds[0][q] + smlds[1][q] + smlds[2][q] + smlds[3][q];
      const float inv = 1.f / tot;
      ushort4 gg = *(const ushort4*)(gsig_b + (size_t)(b * 32 + q) * 128 + h * 32 + c0);
      unsigned short gga[4] = {gg.x, gg.y, gg.z, gg.w};
      unsigned short outa[4];
#pragma unroll
      for (int i2 = 0; i2 < 4; ++i2) {
        const int c = c0 + i2;
        const int ct = c >> 4, lane = g * 16 + (c & 15);
        float s = 0.f;
#pragma unroll
        for (int w2 = 0; w2 < 4; ++w2)
          s += ((const float*)&op[w2 * 4 + mt * 2 + ct][lane])[r];
        outa[i2] = f2bu(s * inv * bu2f(gga[i2]));
      }
      ushort4 ov; ov.x = outa[0]; ov.y = outa[1]; ov.z = outa[2]; ov.w = outa[3];
      *(ushort4*)(o_b + (size_t)(b * 32 + q) * 128 + h * 32 + c0) = ov;
    }
    __syncthreads();
  }
}

// ------------------------------------------------------------------
// N3 (DIAGNOSTIC reps): out = gs * (o @ Wo).
// ------------------------------------------------------------------
__global__ __launch_bounds__(256) void out_kernel(
    const float* __restrict__ Wo, const unsigned short* __restrict__ o_b,
    const unsigned short* __restrict__ gs_b, float* __restrict__ out,
    int reps)
{
  __shared__ unsigned short a_lds[16 * 128];
  const int tid = threadIdx.x;
  const int row0 = blockIdx.x * 16;
  const int l = tid & 63, wv = tid >> 6;
  const int lm = l & 15, kg = l >> 4;
  for (int rep = 0; rep < reps; ++rep) {
    asm volatile("" ::: "memory");
    {
      const int r = tid >> 4, c0 = (tid & 15) << 3;
      uint4 v = *(const uint4*)(o_b + (size_t)(row0 + r) * 128 + c0);
      *(uint4*)&a_lds[r * 128 + (c0 ^ ((r & 7) << 3))] = v;
    }
    __syncthreads();
    f32x4 acc[2] = {};
    const int xa = (lm & 7) << 3;
#pragma unroll
    for (int ks = 0; ks < 4; ++ks) {
      const int ko = ks * 32 + kg * 8;
      short8_t av = *(const short8_t*)&a_lds[lm * 128 + (ko ^ xa)];
#pragma unroll
      for (int ni = 0; ni < 2; ++ni) {
        short8_t bv = wfrag(Wo, nullptr, ko, (wv * 2 + ni) * 16 + lm);
        acc[ni] = __builtin_amdgcn_mfma_f32_16x16x32_bf16(av, bv, acc[ni], 0, 0, 0);
      }
    }
#pragma unroll
    for (int ni = 0; ni < 2; ++ni)
#pragma unroll
      for (int r = 0; r < 4; ++r) {
        const int rl = kg * 4 + r;
        const int n = (wv * 2 + ni) * 16 + lm;
        const float gsv = bu2f(gs_b[(size_t)(row0 + rl) * 128 + n]);
        out[(size_t)(row0 + rl) * 128 + n] = acc[ni][r] * gsv;
      }
    __syncthreads();
  }
}

extern "C" void kernel_launch(void* const* d_in, const int* in_sizes, int n_in,
                              void* d_out, int out_size, void* d_ws, size_t ws_size,
                              hipStream_t stream) {
  const float* act     = (const float*)d_in[0];
  const float* pair    = (const float*)d_in[1];
  const float* cond    = (const float*)d_in[2];
  const float* lns_q   = (const float*)d_in[4];
  const float* Wgate_q = (const float*)d_in[5];
  const float* bgate_q = (const float*)d_in[6];
  const float* Wskip_q = (const float*)d_in[7];
  const float* lns_k   = (const float*)d_in[8];
  const float* Wgate_k = (const float*)d_in[9];
  const float* bgate_k = (const float*)d_in[10];
  const float* Wskip_k = (const float*)d_in[11];
  const float* lnz_w   = (const float*)d_in[12];
  const float* Wq      = (const float*)d_in[13];
  const float* bq      = (const float*)d_in[14];
  const float* Wk      = (const float*)d_in[15];
  const float* Wv      = (const float*)d_in[16];
  const float* Wg      = (const float*)d_in[17];
  const float* Wb      = (const float*)d_in[18];
  const float* Wo      = (const float*)d_in[19];
  const float* Wgs     = (const float*)d_in[20];
  const float* bgs     = (const float*)d_in[21];
  float* out           = (float*)d_out;

  unsigned short* ws = (unsigned short*)d_ws;
  unsigned short* q_b    = ws;
  unsigned short* k_b    = ws + 262144;
  unsigned short* vt_b   = ws + 524288;
  unsigned short* gsig_b = ws + 786432;
  unsigned short* gs_b   = ws + 1048576;
  unsigned short* o_b    = ws + 1310720;
  unsigned short* bias_h = ws + 1572864;

  // DIAGNOSTIC: reps wrap each (idempotent) body so each dispatch exceeds the
  // 158us harness fills and lands in rocprof top-5 with counters.
  // Decode: body_i = row_dur / reps  (N1/40, N2/60, N3/120).
  hipLaunchKernelGGL(bias_proj_kernel, dim3(1344), dim3(256), 0, stream,
                     act, cond, lns_q, lns_k,
                     Wgate_q, Wskip_q, Wgate_k, Wskip_k,
                     Wq, Wk, Wv, Wg, Wgs,
                     bgate_q, bgate_k, bq, bgs,
                     pair, lnz_w, Wb,
                     q_b, k_b, vt_b, gsig_b, gs_b, bias_h, 40);
  hipLaunchKernelGGL(attn_kernel, dim3(256), dim3(256), 0, stream,
                     q_b, k_b, vt_b, gsig_b, bias_h, o_b, 60);
  hipLaunchKernelGGL(out_kernel, dim3(128), dim3(256), 0, stream,
                     Wo, o_b, gs_b, out, 120);
}

// Round 16
// 29.554 us; speedup vs baseline: 26.1530x; 26.1530x over previous
//
#include <hip/hip_runtime.h>
#include <hip/hip_bf16.h>

#define NTOK 2048

typedef __attribute__((ext_vector_type(8))) short short8_t;
typedef __attribute__((ext_vector_type(4))) float f32x4;

__device__ __forceinline__ float bu2f(unsigned short u) {
  unsigned int x = ((unsigned int)u) << 16; float f; __builtin_memcpy(&f, &x, 4); return f;
}
__device__ __forceinline__ unsigned short f2bu(float f) {
  __hip_bfloat16 h = __float2bfloat16(f);
  unsigned short u; __builtin_memcpy(&u, &h, 2); return u;
}
__device__ __forceinline__ float sigm(float x) { return 1.0f / (1.0f + __expf(-x)); }
__device__ __forceinline__ uint4 pack8(const float* v) {
  unsigned short u[8];
#pragma unroll
  for (int i = 0; i < 8; ++i) u[i] = f2bu(v[i]);
  uint4 r; __builtin_memcpy(&r, u, 16); return r;
}
__device__ __forceinline__ short8_t pk8s(const float* v) {
  unsigned short u[8];
#pragma unroll
  for (int i = 0; i < 8; ++i) u[i] = f2bu(v[i]);
  short8_t r; __builtin_memcpy(&r, u, 16); return r;
}

__device__ __forceinline__ short8_t wfrag(const float* __restrict__ W,
                                          const float* __restrict__ lns,
                                          int ko, int n) {
  float v[8];
#pragma unroll
  for (int i = 0; i < 8; ++i) v[i] = W[(size_t)(ko + i) * 128 + n];
  if (lns) {
    float4 l0 = *(const float4*)(lns + ko);
    float4 l1 = *(const float4*)(lns + ko + 4);
    v[0] *= l0.x; v[1] *= l0.y; v[2] *= l0.z; v[3] *= l0.w;
    v[4] *= l1.x; v[5] *= l1.y; v[6] *= l1.z; v[7] *= l1.w;
  }
  return pk8s(v);
}

__device__ __forceinline__ void gemm_dw(const unsigned short* a_lds,
                                        const float* __restrict__ W,
                                        const float* __restrict__ lns,
                                        int lm, int kg, int wv, f32x4 acc[2][2]) {
  const int xa = (lm & 7) << 3;
#pragma unroll
  for (int ks = 0; ks < 4; ++ks) {
    const int ko = ks * 32 + kg * 8;
    short8_t av[2], bv[2];
#pragma unroll
    for (int mi = 0; mi < 2; ++mi)
      av[mi] = *(const short8_t*)&a_lds[(mi * 16 + lm) * 128 + (ko ^ xa)];
#pragma unroll
    for (int ni = 0; ni < 2; ++ni)
      bv[ni] = wfrag(W, lns, ko, (wv * 2 + ni) * 16 + lm);
#pragma unroll
    for (int mi = 0; mi < 2; ++mi)
#pragma unroll
      for (int ni = 0; ni < 2; ++ni)
        acc[mi][ni] = __builtin_amdgcn_mfma_f32_16x16x32_bf16(av[mi], bv[ni], acc[mi][ni], 0, 0, 0);
  }
}

// ------------------------------------------------------------------
// K1: windowed pair bias only (low VGPR -> high occupancy). 1024 blocks.
// ------------------------------------------------------------------
__global__ __launch_bounds__(256) void bias_kernel(
    const float* __restrict__ pair, const float* __restrict__ lnz_w,
    const float* __restrict__ Wb, unsigned short* __restrict__ bias_h)
{
  __shared__ float lw[16];
  __shared__ float wbz[16][4];
  const int tid = threadIdx.x;
  if (tid < 16) lw[tid] = lnz_w[tid];
  if (tid < 64) wbz[tid >> 2][tid & 3] = Wb[tid];
  __syncthreads();
  const int idx = blockIdx.x * 256 + tid;
  const int i = idx >> 7, jw = idx & 127;
  const int j = ((i >> 5) << 5) - 48 + jw;
  float bo[4] = {-1e9f, -1e9f, -1e9f, -1e9f};
  if (j >= 0 && j < NTOK) {
    const float4* p = (const float4*)(pair + ((size_t)i * NTOK + j) * 16);
    float4 z0 = p[0], z1 = p[1], z2 = p[2], z3 = p[3];
    float z[16] = {z0.x, z0.y, z0.z, z0.w, z1.x, z1.y, z1.z, z1.w,
                   z2.x, z2.y, z2.z, z2.w, z3.x, z3.y, z3.z, z3.w};
    float s = 0.f, ss = 0.f;
#pragma unroll
    for (int c = 0; c < 16; ++c) { s += z[c]; ss += z[c]*z[c]; }
    const float m = s * (1.f/16.f), v = ss * (1.f/16.f) - m*m;
    const float r = rsqrtf(v + 1e-5f);
    bo[0] = bo[1] = bo[2] = bo[3] = 0.f;
#pragma unroll
    for (int c = 0; c < 16; ++c) {
      const float zn = (z[c] - m) * r * lw[c];
      bo[0] += zn * wbz[c][0]; bo[1] += zn * wbz[c][1];
      bo[2] += zn * wbz[c][2]; bo[3] += zn * wbz[c][3];
    }
  }
#pragma unroll
  for (int h = 0; h < 4; ++h)
    bias_h[(size_t)h * (NTOK * 128) + idx] = f2bu(bo[h]);
}

// ------------------------------------------------------------------
// K2: self-contained projections. 320 blocks = 64 rt x {q,g,k,v,gs}.
// ------------------------------------------------------------------
__global__ __launch_bounds__(256) void proj_kernel(
    const float* __restrict__ act, const float* __restrict__ cond,
    const float* __restrict__ lns_q, const float* __restrict__ lns_k,
    const float* __restrict__ WgQ, const float* __restrict__ WsQ,
    const float* __restrict__ WgK, const float* __restrict__ WsK,
    const float* __restrict__ Wq, const float* __restrict__ Wk,
    const float* __restrict__ Wv, const float* __restrict__ Wg,
    const float* __restrict__ Wgs,
    const float* __restrict__ bgate_q, const float* __restrict__ bgate_k,
    const float* __restrict__ bq, const float* __restrict__ bgs,
    unsigned short* __restrict__ q_b, unsigned short* __restrict__ k_b,
    unsigned short* __restrict__ vt_b, unsigned short* __restrict__ gsig_b,
    unsigned short* __restrict__ gs_b)
{
  __shared__ unsigned short a_lds[32 * 128];
  __shared__ unsigned short xn_lds[32 * 136];
  __shared__ unsigned short a2_lds[32 * 128];
  const int tid = threadIdx.x;
  const int br = blockIdx.x / 64;       // 0:q 1:g 2:k 3:v 4:gs
  const int rt = blockIdx.x % 64;
  const int row0 = rt * 32;
  const int l = tid & 63, wv = tid >> 6;
  const int lm = l & 15, kg = l >> 4;

  { // LN stage
    const int r = tid >> 3;
    const int c0 = (tid & 7) << 4;
    float xv[16], cv[16];
    const float4* ap = (const float4*)(act + (size_t)(row0 + r) * 128 + c0);
    const float4* cp = (const float4*)(cond + (size_t)(row0 + r) * 128 + c0);
#pragma unroll
    for (int i = 0; i < 4; ++i) {
      float4 a4 = ap[i], b4 = cp[i];
      xv[4*i+0]=a4.x; xv[4*i+1]=a4.y; xv[4*i+2]=a4.z; xv[4*i+3]=a4.w;
      cv[4*i+0]=b4.x; cv[4*i+1]=b4.y; cv[4*i+2]=b4.z; cv[4*i+3]=b4.w;
    }
    float sx=0.f, sxx=0.f, sc=0.f, scc=0.f;
#pragma unroll
    for (int i = 0; i < 16; ++i) { sx+=xv[i]; sxx+=xv[i]*xv[i]; sc+=cv[i]; scc+=cv[i]*cv[i]; }
#pragma unroll
    for (int m = 1; m < 8; m <<= 1) {
      sx += __shfl_xor(sx, m); sxx += __shfl_xor(sxx, m);
      sc += __shfl_xor(sc, m); scc += __shfl_xor(scc, m);
    }
    const float mx = sx * (1.f/128.f), vx = sxx*(1.f/128.f) - mx*mx;
    const float mc = sc * (1.f/128.f), vc = scc*(1.f/128.f) - mc*mc;
    const float rx = rsqrtf(vx + 1e-5f), rc = rsqrtf(vc + 1e-5f);
    float xo[16], so[16];
#pragma unroll
    for (int i = 0; i < 16; ++i) { xo[i] = (xv[i]-mx)*rx; so[i] = (cv[i]-mc)*rc; }
    const int x = (r & 7) << 3;
    if (br == 4) {
      *(uint4*)&a_lds[r * 128 + (c0 ^ x)] = pack8(cv);
      *(uint4*)&a_lds[r * 128 + ((c0 + 8) ^ x)] = pack8(cv + 8);
    } else {
      *(uint4*)&a_lds[r * 128 + (c0 ^ x)] = pack8(so);
      *(uint4*)&a_lds[r * 128 + ((c0 + 8) ^ x)] = pack8(so + 8);
      *(uint4*)&xn_lds[r * 136 + c0] = pack8(xo);
      *(uint4*)&xn_lds[r * 136 + c0 + 8] = pack8(xo + 8);
    }
  }
  __syncthreads();

  if (br == 4) {
    f32x4 acc[2][2] = {};
    gemm_dw(a_lds, Wgs, nullptr, lm, kg, wv, acc);
    float bgv[2];
#pragma unroll
    for (int ni = 0; ni < 2; ++ni) bgv[ni] = bgs[(wv * 2 + ni) * 16 + lm];
#pragma unroll
    for (int mi = 0; mi < 2; ++mi)
#pragma unroll
      for (int ni = 0; ni < 2; ++ni)
#pragma unroll
        for (int r = 0; r < 4; ++r) {
          const int rl = mi * 16 + kg * 4 + r;
          const int n = (wv * 2 + ni) * 16 + lm;
          gs_b[(size_t)(row0 + rl) * 128 + n] = f2bu(sigm(acc[mi][ni][r] + bgv[ni]));
        }
    return;
  }

  const bool useq = (br < 2);
  const float* Wgt = useq ? WgQ : WgK;
  const float* Wsk = useq ? WsQ : WsK;
  const float* lns = useq ? lns_q : lns_k;
  const float* bg  = useq ? bgate_q : bgate_k;

  f32x4 ag[2][2] = {}, as2[2][2] = {};
  gemm_dw(a_lds, Wgt, lns, lm, kg, wv, ag);
  gemm_dw(a_lds, Wsk, lns, lm, kg, wv, as2);
  { // combine: a = sigm(gate+bg)*xn + skip -> a2 (swizzled bf16)
    float bgv[2];
#pragma unroll
    for (int ni = 0; ni < 2; ++ni) bgv[ni] = bg[(wv * 2 + ni) * 16 + lm];
#pragma unroll
    for (int mi = 0; mi < 2; ++mi)
#pragma unroll
      for (int ni = 0; ni < 2; ++ni)
#pragma unroll
        for (int r = 0; r < 4; ++r) {
          const int rl = mi * 16 + kg * 4 + r;
          const int n = (wv * 2 + ni) * 16 + lm;
          const float gate = sigm(ag[mi][ni][r] + bgv[ni]);
          const float a = gate * bu2f(xn_lds[rl * 136 + n]) + as2[mi][ni][r];
          a2_lds[rl * 128 + (n ^ ((rl & 7) << 3))] = f2bu(a);
        }
  }
  __syncthreads();

  const float* Wout = (br == 0) ? Wq : (br == 1) ? Wg : (br == 2) ? Wk : Wv;
  f32x4 ao[2][2] = {};
  gemm_dw(a2_lds, Wout, nullptr, lm, kg, wv, ao);

  if (br == 3) {
#pragma unroll
    for (int mi = 0; mi < 2; ++mi)
#pragma unroll
      for (int ni = 0; ni < 2; ++ni) {
        const int n = (wv * 2 + ni) * 16 + lm;
        const int tok0 = row0 + mi * 16 + kg * 4;
        ushort4 o;
        o.x = f2bu(ao[mi][ni][0]); o.y = f2bu(ao[mi][ni][1]);
        o.z = f2bu(ao[mi][ni][2]); o.w = f2bu(ao[mi][ni][3]);
        *(ushort4*)(vt_b + (size_t)n * NTOK + tok0) = o;
      }
    return;
  }
  const float scale = 0.17677669529663687f;
  float bqv[2] = {0.f, 0.f};
  if (br == 0) {
#pragma unroll
    for (int ni = 0; ni < 2; ++ni) bqv[ni] = bq[(wv * 2 + ni) * 16 + lm];
  }
  unsigned short* dst = (br == 0) ? q_b : (br == 1) ? gsig_b : k_b;
#pragma unroll
  for (int mi = 0; mi < 2; ++mi)
#pragma unroll
    for (int ni = 0; ni < 2; ++ni)
#pragma unroll
      for (int r = 0; r < 4; ++r) {
        const int rl = mi * 16 + kg * 4 + r;
        const int n = (wv * 2 + ni) * 16 + lm;
        float v = ao[mi][ni][r];
        if (br == 0) v = (v + bqv[ni]) * scale;
        else if (br == 1) v = sigm(v);
        dst[(size_t)(row0 + rl) * 128 + n] = f2bu(v);
      }
}

// ------------------------------------------------------------------
// K3: attention per (qblock, head). 256 blocks x 256 threads.
// PV restructured: wave computes rows (wv&1)*16, cols (wv>>1)*16 over ALL
// 128 keys via chained MFMA (bit-identical sum order); no op buffer.
// ------------------------------------------------------------------
__global__ __launch_bounds__(256) void attn_kernel(
    const unsigned short* __restrict__ q_b, const unsigned short* __restrict__ k_b,
    const unsigned short* __restrict__ vt_b, const unsigned short* __restrict__ gsig_b,
    const unsigned short* __restrict__ bias_h, unsigned short* __restrict__ o_b)
{
  __shared__ unsigned short k_lds[128 * 64];
  __shared__ unsigned short vt[32 * 128];
  __shared__ unsigned short p_lds[32 * 128];
  __shared__ unsigned short q_lds[32 * 64];
  __shared__ unsigned short bias_lds[32 * 136];
  __shared__ float mxlds[4][32];
  __shared__ float smlds[4][32];
  const int tid = threadIdx.x;
  const int h = blockIdx.x & 3, b = blockIdx.x >> 2;
  const int j0 = b * 32 - 48;
  const int l = tid & 63, wv = tid >> 6;
  const int lm = l & 15, kg = l >> 4;

  { // Q stage
    const int r = tid >> 3, c0 = (tid & 7) << 2;
    ushort4 v = *(const ushort4*)(q_b + (size_t)(b * 32 + r) * 128 + h * 32 + c0);
    *(ushort4*)&q_lds[r * 64 + (c0 ^ ((r & 7) << 3))] = v;
  }
  { // bias stage
    const int r = tid >> 3, c0 = (tid & 7) << 4;
    const uint4* g = (const uint4*)(bias_h + (size_t)h * (NTOK * 128) + (size_t)(b * 32 + r) * 128 + c0);
    uint4 v0 = g[0], v1 = g[1];
    *(uint4*)&bias_lds[r * 136 + c0] = v0;
    *(uint4*)&bias_lds[r * 136 + c0 + 8] = v1;
  }
  { // K stage
    const int jw = tid >> 1, cb = (tid & 1) << 4;
    const int j = j0 + jw;
    uint4 kv0 = {0,0,0,0}, kv1 = {0,0,0,0};
    if (j >= 0 && j < NTOK) {
      const uint4* gk = (const uint4*)(k_b + (size_t)j * 128 + h * 32 + cb);
      kv0 = gk[0]; kv1 = gk[1];
    }
    const int xk = (jw & 7) << 3;
    *(uint4*)&k_lds[jw * 64 + (cb ^ xk)] = kv0;
    *(uint4*)&k_lds[jw * 64 + ((cb + 8) ^ xk)] = kv1;
  }
  { // V stage from vt_b
    const int c = tid >> 3, koff = (tid & 7) << 4;
    const int j = j0 + koff;
    uint4 v0 = {0,0,0,0}, v1 = {0,0,0,0};
    if (j >= 0 && j + 15 < NTOK) {
      const uint4* gv = (const uint4*)(vt_b + (size_t)(h * 32 + c) * NTOK + j);
      v0 = gv[0]; v1 = gv[1];
    }
    const int xc = (c & 7) << 3;
    *(uint4*)&vt[c * 128 + (koff ^ xc)] = v0;
    *(uint4*)&vt[c * 128 + ((koff + 8) ^ xc)] = v1;
  }
  __syncthreads();

  // QK^T
  f32x4 sc[2][2] = {};
  {
    const int xa = (lm & 7) << 3;
    short8_t aq[2], bk[2];
#pragma unroll
    for (int mi = 0; mi < 2; ++mi)
      aq[mi] = *(const short8_t*)&q_lds[(mi * 16 + lm) * 64 + ((kg * 8) ^ xa)];
#pragma unroll
    for (int ni = 0; ni < 2; ++ni) {
      const int key = (wv * 2 + ni) * 16 + lm;
      bk[ni] = *(const short8_t*)&k_lds[key * 64 + ((kg * 8) ^ ((key & 7) << 3))];
    }
#pragma unroll
    for (int mi = 0; mi < 2; ++mi)
#pragma unroll
      for (int ni = 0; ni < 2; ++ni)
        sc[mi][ni] = __builtin_amdgcn_mfma_f32_16x16x32_bf16(aq[mi], bk[ni], sc[mi][ni], 0, 0, 0);
  }
  float sv[2][2][4];
#pragma unroll
  for (int mi = 0; mi < 2; ++mi)
#pragma unroll
    for (int ni = 0; ni < 2; ++ni)
#pragma unroll
      for (int r = 0; r < 4; ++r) {
        const int q = mi * 16 + kg * 4 + r;
        const int key = (wv * 2 + ni) * 16 + lm;
        sv[mi][ni][r] = sc[mi][ni][r] + bu2f(bias_lds[q * 136 + key]);
      }
#pragma unroll
  for (int mi = 0; mi < 2; ++mi)
#pragma unroll
    for (int r = 0; r < 4; ++r) {
      float m0 = fmaxf(sv[mi][0][r], sv[mi][1][r]);
#pragma unroll
      for (int msk = 1; msk < 16; msk <<= 1) m0 = fmaxf(m0, __shfl_xor(m0, msk));
      if (lm == 0) mxlds[wv][mi * 16 + kg * 4 + r] = m0;
    }
  __syncthreads();
#pragma unroll
  for (int mi = 0; mi < 2; ++mi)
#pragma unroll
    for (int r = 0; r < 4; ++r) {
      const int q = mi * 16 + kg * 4 + r;
      const float m = fmaxf(fmaxf(mxlds[0][q], mxlds[1][q]), fmaxf(mxlds[2][q], mxlds[3][q]));
      float s = 0.f;
#pragma unroll
      for (int ni = 0; ni < 2; ++ni) {
        const float e = __expf(sv[mi][ni][r] - m);
        const int key = (wv * 2 + ni) * 16 + lm;
        p_lds[q * 128 + ((key & 7) | ((key & 120) ^ ((q & 7) << 3)))] = f2bu(e);
        s += e;
      }
#pragma unroll
      for (int msk = 1; msk < 16; msk <<= 1) s += __shfl_xor(s, msk);
      if (lm == 0) smlds[wv][q] = s;
    }
  __syncthreads();   // all waves' P and sums visible

  // PV: wave (wv) -> rows rh=(wv&1)*16, cols ch=(wv>>1)*16, keys 0..127
  {
    const int rh = (wv & 1) << 4, ch = (wv >> 1) << 4;
    const int rowl = rh + lm;
    const int coll = ch + lm;
    const int xr = (rowl & 7) << 3, xc = (coll & 7) << 3;
    f32x4 acc = {};
#pragma unroll
    for (int ks = 0; ks < 4; ++ks) {
      const int ko = ks * 32 + kg * 8;
      short8_t pa = *(const short8_t*)&p_lds[rowl * 128 + (ko ^ xr)];
      short8_t vb = *(const short8_t*)&vt[coll * 128 + (ko ^ xc)];
      acc = __builtin_amdgcn_mfma_f32_16x16x32_bf16(pa, vb, acc, 0, 0, 0);
    }
#pragma unroll
    for (int r = 0; r < 4; ++r) {
      const int row = rh + kg * 4 + r;
      const int col = ch + lm;
      const float tot = smlds[0][row] + smlds[1][row] + smlds[2][row] + smlds[3][row];
      const float inv = 1.f / tot;
      const float gsv = bu2f(gsig_b[(size_t)(b * 32 + row) * 128 + h * 32 + col]);
      o_b[(size_t)(b * 32 + row) * 128 + h * 32 + col] = f2bu(acc[r] * inv * gsv);
    }
  }
}

// ------------------------------------------------------------------
// K4: out = gs * (o @ Wo), direct-f32 Wo fragments. 128 blocks x 16 rows.
// ------------------------------------------------------------------
__global__ __launch_bounds__(256) void out_kernel(
    const float* __restrict__ Wo, const unsigned short* __restrict__ o_b,
    const unsigned short* __restrict__ gs_b, float* __restrict__ out)
{
  __shared__ unsigned short a_lds[16 * 128];
  const int tid = threadIdx.x;
  const int row0 = blockIdx.x * 16;
  const int l = tid & 63, wv = tid >> 6;
  const int lm = l & 15, kg = l >> 4;
  {
    const int r = tid >> 4, c0 = (tid & 15) << 3;
    uint4 v = *(const uint4*)(o_b + (size_t)(row0 + r) * 128 + c0);
    *(uint4*)&a_lds[r * 128 + (c0 ^ ((r & 7) << 3))] = v;
  }
  __syncthreads();
  f32x4 acc[2] = {};
  const int xa = (lm & 7) << 3;
#pragma unroll
  for (int ks = 0; ks < 4; ++ks) {
    const int ko = ks * 32 + kg * 8;
    short8_t av = *(const short8_t*)&a_lds[lm * 128 + (ko ^ xa)];
#pragma unroll
    for (int ni = 0; ni < 2; ++ni) {
      short8_t bv = wfrag(Wo, nullptr, ko, (wv * 2 + ni) * 16 + lm);
      acc[ni] = __builtin_amdgcn_mfma_f32_16x16x32_bf16(av, bv, acc[ni], 0, 0, 0);
    }
  }
#pragma unroll
  for (int ni = 0; ni < 2; ++ni)
#pragma unroll
    for (int r = 0; r < 4; ++r) {
      const int rl = kg * 4 + r;
      const int n = (wv * 2 + ni) * 16 + lm;
      const float gsv = bu2f(gs_b[(size_t)(row0 + rl) * 128 + n]);
      out[(size_t)(row0 + rl) * 128 + n] = acc[ni][r] * gsv;
    }
}

extern "C" void kernel_launch(void* const* d_in, const int* in_sizes, int n_in,
                              void* d_out, int out_size, void* d_ws, size_t ws_size,
                              hipStream_t stream) {
  const float* act     = (const float*)d_in[0];
  const float* pair    = (const float*)d_in[1];
  const float* cond    = (const float*)d_in[2];
  const float* lns_q   = (const float*)d_in[4];
  const float* Wgate_q = (const float*)d_in[5];
  const float* bgate_q = (const float*)d_in[6];
  const float* Wskip_q = (const float*)d_in[7];
  const float* lns_k   = (const float*)d_in[8];
  const float* Wgate_k = (const float*)d_in[9];
  const float* bgate_k = (const float*)d_in[10];
  const float* Wskip_k = (const float*)d_in[11];
  const float* lnz_w   = (const float*)d_in[12];
  const float* Wq      = (const float*)d_in[13];
  const float* bq      = (const float*)d_in[14];
  const float* Wk      = (const float*)d_in[15];
  const float* Wv      = (const float*)d_in[16];
  const float* Wg      = (const float*)d_in[17];
  const float* Wb      = (const float*)d_in[18];
  const float* Wo      = (const float*)d_in[19];
  const float* Wgs     = (const float*)d_in[20];
  const float* bgs     = (const float*)d_in[21];
  float* out           = (float*)d_out;

  unsigned short* ws = (unsigned short*)d_ws;
  unsigned short* q_b    = ws;
  unsigned short* k_b    = ws + 262144;
  unsigned short* vt_b   = ws + 524288;             // [128 dims][2048 tokens]
  unsigned short* gsig_b = ws + 786432;
  unsigned short* gs_b   = ws + 1048576;
  unsigned short* o_b    = ws + 1310720;
  unsigned short* bias_h = ws + 1572864;            // 4*2048*128

  hipLaunchKernelGGL(bias_kernel, dim3(1024), dim3(256), 0, stream,
                     pair, lnz_w, Wb, bias_h);
  hipLaunchKernelGGL(proj_kernel, dim3(320), dim3(256), 0, stream,
                     act, cond, lns_q, lns_k,
                     Wgate_q, Wskip_q, Wgate_k, Wskip_k,
                     Wq, Wk, Wv, Wg, Wgs,
                     bgate_q, bgate_k, bq, bgs,
                     q_b, k_b, vt_b, gsig_b, gs_b);
  hipLaunchKernelGGL(attn_kernel, dim3(256), dim3(256), 0, stream,
                     q_b, k_b, vt_b, gsig_b, bias_h, o_b);
  hipLaunchKernelGGL(out_kernel, dim3(128), dim3(256), 0, stream,
                     Wo, o_b, gs_b, out);
}

// Round 17
// 25.700 us; speedup vs baseline: 30.0750x; 1.1500x over previous
//
#include <hip/hip_runtime.h>
#include <hip/hip_bf16.h>

#define NTOK 2048

typedef __attribute__((ext_vector_type(8))) short short8_t;
typedef __attribute__((ext_vector_type(4))) float f32x4;

__device__ __forceinline__ float bu2f(unsigned short u) {
  unsigned int x = ((unsigned int)u) << 16; float f; __builtin_memcpy(&f, &x, 4); return f;
}
__device__ __forceinline__ unsigned short f2bu(float f) {
  __hip_bfloat16 h = __float2bfloat16(f);
  unsigned short u; __builtin_memcpy(&u, &h, 2); return u;
}
__device__ __forceinline__ float sigm(float x) { return 1.0f / (1.0f + __expf(-x)); }
__device__ __forceinline__ uint4 pack8(const float* v) {
  unsigned short u[8];
#pragma unroll
  for (int i = 0; i < 8; ++i) u[i] = f2bu(v[i]);
  uint4 r; __builtin_memcpy(&r, u, 16); return r;
}
__device__ __forceinline__ short8_t pk8s(const float* v) {
  unsigned short u[8];
#pragma unroll
  for (int i = 0; i < 8; ++i) u[i] = f2bu(v[i]);
  short8_t r; __builtin_memcpy(&r, u, 16); return r;
}

__device__ __forceinline__ short8_t wfrag(const float* __restrict__ W,
                                          const float* __restrict__ lns,
                                          int ko, int n) {
  float v[8];
#pragma unroll
  for (int i = 0; i < 8; ++i) v[i] = W[(size_t)(ko + i) * 128 + n];
  if (lns) {
    float4 l0 = *(const float4*)(lns + ko);
    float4 l1 = *(const float4*)(lns + ko + 4);
    v[0] *= l0.x; v[1] *= l0.y; v[2] *= l0.z; v[3] *= l0.w;
    v[4] *= l1.x; v[5] *= l1.y; v[6] *= l1.z; v[7] *= l1.w;
  }
  return pk8s(v);
}

__device__ __forceinline__ void gemm_dw(const unsigned short* a_lds,
                                        const float* __restrict__ W,
                                        const float* __restrict__ lns,
                                        int lm, int kg, int wv, f32x4 acc[2][2]) {
  const int xa = (lm & 7) << 3;
#pragma unroll
  for (int ks = 0; ks < 4; ++ks) {
    const int ko = ks * 32 + kg * 8;
    short8_t av[2], bv[2];
#pragma unroll
    for (int mi = 0; mi < 2; ++mi)
      av[mi] = *(const short8_t*)&a_lds[(mi * 16 + lm) * 128 + (ko ^ xa)];
#pragma unroll
    for (int ni = 0; ni < 2; ++ni)
      bv[ni] = wfrag(W, lns, ko, (wv * 2 + ni) * 16 + lm);
#pragma unroll
    for (int mi = 0; mi < 2; ++mi)
#pragma unroll
      for (int ni = 0; ni < 2; ++ni)
        acc[mi][ni] = __builtin_amdgcn_mfma_f32_16x16x32_bf16(av[mi], bv[ni], acc[mi][ni], 0, 0, 0);
  }
}

// ------------------------------------------------------------------
// N1 (r14 verbatim): blocks [0,320) = self-contained projections (FIRST);
//     blocks [320,1344) = windowed pair bias (BW-bound, streams underneath).
// ------------------------------------------------------------------
__global__ __launch_bounds__(256) void bias_proj_kernel(
    const float* __restrict__ act, const float* __restrict__ cond,
    const float* __restrict__ lns_q, const float* __restrict__ lns_k,
    const float* __restrict__ WgQ, const float* __restrict__ WsQ,
    const float* __restrict__ WgK, const float* __restrict__ WsK,
    const float* __restrict__ Wq, const float* __restrict__ Wk,
    const float* __restrict__ Wv, const float* __restrict__ Wg,
    const float* __restrict__ Wgs,
    const float* __restrict__ bgate_q, const float* __restrict__ bgate_k,
    const float* __restrict__ bq, const float* __restrict__ bgs,
    const float* __restrict__ pair, const float* __restrict__ lnz_w,
    const float* __restrict__ Wb,
    unsigned short* __restrict__ q_b, unsigned short* __restrict__ k_b,
    unsigned short* __restrict__ vt_b, unsigned short* __restrict__ gsig_b,
    unsigned short* __restrict__ gs_b, unsigned short* __restrict__ bias_h)
{
  __shared__ unsigned short a_lds[32 * 128];
  __shared__ unsigned short xn_lds[32 * 136];
  __shared__ unsigned short a2_lds[32 * 128];
  __shared__ float lw[16];
  __shared__ float wbz[16][4];
  const int tid = threadIdx.x;
  const int bid = blockIdx.x;

  if (bid >= 320) {
    // ---- windowed pair bias ----
    if (tid < 16) lw[tid] = lnz_w[tid];
    if (tid < 64) wbz[tid >> 2][tid & 3] = Wb[tid];
    __syncthreads();
    const int idx = (bid - 320) * 256 + tid;
    const int i = idx >> 7, jw = idx & 127;
    const int j = ((i >> 5) << 5) - 48 + jw;
    float bo[4] = {-1e9f, -1e9f, -1e9f, -1e9f};
    if (j >= 0 && j < NTOK) {
      const float4* p = (const float4*)(pair + ((size_t)i * NTOK + j) * 16);
      float4 z0 = p[0], z1 = p[1], z2 = p[2], z3 = p[3];
      float z[16] = {z0.x, z0.y, z0.z, z0.w, z1.x, z1.y, z1.z, z1.w,
                     z2.x, z2.y, z2.z, z2.w, z3.x, z3.y, z3.z, z3.w};
      float s = 0.f, ss = 0.f;
#pragma unroll
      for (int c = 0; c < 16; ++c) { s += z[c]; ss += z[c]*z[c]; }
      const float m = s * (1.f/16.f), v = ss * (1.f/16.f) - m*m;
      const float r = rsqrtf(v + 1e-5f);
      bo[0] = bo[1] = bo[2] = bo[3] = 0.f;
#pragma unroll
      for (int c = 0; c < 16; ++c) {
        const float zn = (z[c] - m) * r * lw[c];
        bo[0] += zn * wbz[c][0]; bo[1] += zn * wbz[c][1];
        bo[2] += zn * wbz[c][2]; bo[3] += zn * wbz[c][3];
      }
    }
#pragma unroll
    for (int h = 0; h < 4; ++h)
      bias_h[(size_t)h * (NTOK * 128) + idx] = f2bu(bo[h]);
    return;
  }

  // ---- self-contained projection ----
  const int br = bid / 64;       // 0:q 1:g 2:k 3:v 4:gs
  const int rt = bid % 64;
  const int row0 = rt * 32;
  const int l = tid & 63, wv = tid >> 6;
  const int lm = l & 15, kg = l >> 4;

  { // LN stage
    const int r = tid >> 3;
    const int c0 = (tid & 7) << 4;
    float xv[16], cv[16];
    const float4* ap = (const float4*)(act + (size_t)(row0 + r) * 128 + c0);
    const float4* cp = (const float4*)(cond + (size_t)(row0 + r) * 128 + c0);
#pragma unroll
    for (int i = 0; i < 4; ++i) {
      float4 a4 = ap[i], b4 = cp[i];
      xv[4*i+0]=a4.x; xv[4*i+1]=a4.y; xv[4*i+2]=a4.z; xv[4*i+3]=a4.w;
      cv[4*i+0]=b4.x; cv[4*i+1]=b4.y; cv[4*i+2]=b4.z; cv[4*i+3]=b4.w;
    }
    float sx=0.f, sxx=0.f, sc=0.f, scc=0.f;
#pragma unroll
    for (int i = 0; i < 16; ++i) { sx+=xv[i]; sxx+=xv[i]*xv[i]; sc+=cv[i]; scc+=cv[i]*cv[i]; }
#pragma unroll
    for (int m = 1; m < 8; m <<= 1) {
      sx += __shfl_xor(sx, m); sxx += __shfl_xor(sxx, m);
      sc += __shfl_xor(sc, m); scc += __shfl_xor(scc, m);
    }
    const float mx = sx * (1.f/128.f), vx = sxx*(1.f/128.f) - mx*mx;
    const float mc = sc * (1.f/128.f), vc = scc*(1.f/128.f) - mc*mc;
    const float rx = rsqrtf(vx + 1e-5f), rc = rsqrtf(vc + 1e-5f);
    float xo[16], so[16];
#pragma unroll
    for (int i = 0; i < 16; ++i) { xo[i] = (xv[i]-mx)*rx; so[i] = (cv[i]-mc)*rc; }
    const int x = (r & 7) << 3;
    if (br == 4) {
      *(uint4*)&a_lds[r * 128 + (c0 ^ x)] = pack8(cv);
      *(uint4*)&a_lds[r * 128 + ((c0 + 8) ^ x)] = pack8(cv + 8);
    } else {
      *(uint4*)&a_lds[r * 128 + (c0 ^ x)] = pack8(so);
      *(uint4*)&a_lds[r * 128 + ((c0 + 8) ^ x)] = pack8(so + 8);
      *(uint4*)&xn_lds[r * 136 + c0] = pack8(xo);
      *(uint4*)&xn_lds[r * 136 + c0 + 8] = pack8(xo + 8);
    }
  }
  __syncthreads();

  if (br == 4) {
    f32x4 acc[2][2] = {};
    gemm_dw(a_lds, Wgs, nullptr, lm, kg, wv, acc);
    float bgv[2];
#pragma unroll
    for (int ni = 0; ni < 2; ++ni) bgv[ni] = bgs[(wv * 2 + ni) * 16 + lm];
#pragma unroll
    for (int mi = 0; mi < 2; ++mi)
#pragma unroll
      for (int ni = 0; ni < 2; ++ni)
#pragma unroll
        for (int r = 0; r < 4; ++r) {
          const int rl = mi * 16 + kg * 4 + r;
          const int n = (wv * 2 + ni) * 16 + lm;
          gs_b[(size_t)(row0 + rl) * 128 + n] = f2bu(sigm(acc[mi][ni][r] + bgv[ni]));
        }
    return;
  }

  const bool useq = (br < 2);
  const float* Wgt = useq ? WgQ : WgK;
  const float* Wsk = useq ? WsQ : WsK;
  const float* lns = useq ? lns_q : lns_k;
  const float* bg  = useq ? bgate_q : bgate_k;

  f32x4 ag[2][2] = {}, as2[2][2] = {};
  gemm_dw(a_lds, Wgt, lns, lm, kg, wv, ag);
  gemm_dw(a_lds, Wsk, lns, lm, kg, wv, as2);
  { // combine: a = sigm(gate+bg)*xn + skip -> a2 (swizzled bf16)
    float bgv[2];
#pragma unroll
    for (int ni = 0; ni < 2; ++ni) bgv[ni] = bg[(wv * 2 + ni) * 16 + lm];
#pragma unroll
    for (int mi = 0; mi < 2; ++mi)
#pragma unroll
      for (int ni = 0; ni < 2; ++ni)
#pragma unroll
        for (int r = 0; r < 4; ++r) {
          const int rl = mi * 16 + kg * 4 + r;
          const int n = (wv * 2 + ni) * 16 + lm;
          const float gate = sigm(ag[mi][ni][r] + bgv[ni]);
          const float a = gate * bu2f(xn_lds[rl * 136 + n]) + as2[mi][ni][r];
          a2_lds[rl * 128 + (n ^ ((rl & 7) << 3))] = f2bu(a);
        }
  }
  __syncthreads();

  const float* Wout = (br == 0) ? Wq : (br == 1) ? Wg : (br == 2) ? Wk : Wv;
  f32x4 ao[2][2] = {};
  gemm_dw(a2_lds, Wout, nullptr, lm, kg, wv, ao);

  if (br == 3) {
#pragma unroll
    for (int mi = 0; mi < 2; ++mi)
#pragma unroll
      for (int ni = 0; ni < 2; ++ni) {
        const int n = (wv * 2 + ni) * 16 + lm;
        const int tok0 = row0 + mi * 16 + kg * 4;
        ushort4 o;
        o.x = f2bu(ao[mi][ni][0]); o.y = f2bu(ao[mi][ni][1]);
        o.z = f2bu(ao[mi][ni][2]); o.w = f2bu(ao[mi][ni][3]);
        *(ushort4*)(vt_b + (size_t)n * NTOK + tok0) = o;
      }
    return;
  }
  const float scale = 0.17677669529663687f;
  float bqv[2] = {0.f, 0.f};
  if (br == 0) {
#pragma unroll
    for (int ni = 0; ni < 2; ++ni) bqv[ni] = bq[(wv * 2 + ni) * 16 + lm];
  }
  unsigned short* dst = (br == 0) ? q_b : (br == 1) ? gsig_b : k_b;
#pragma unroll
  for (int mi = 0; mi < 2; ++mi)
#pragma unroll
    for (int ni = 0; ni < 2; ++ni)
#pragma unroll
      for (int r = 0; r < 4; ++r) {
        const int rl = mi * 16 + kg * 4 + r;
        const int n = (wv * 2 + ni) * 16 + lm;
        float v = ao[mi][ni][r];
        if (br == 0) v = (v + bqv[ni]) * scale;
        else if (br == 1) v = sigm(v);
        dst[(size_t)(row0 + rl) * 128 + n] = f2bu(v);
      }
}

// ------------------------------------------------------------------
// N2 (r16 verbatim): attention per (qblock, head). Row/col-split PV,
// no op buffer (LDS 46 KB).
// ------------------------------------------------------------------
__global__ __launch_bounds__(256) void attn_kernel(
    const unsigned short* __restrict__ q_b, const unsigned short* __restrict__ k_b,
    const unsigned short* __restrict__ vt_b, const unsigned short* __restrict__ gsig_b,
    const unsigned short* __restrict__ bias_h, unsigned short* __restrict__ o_b)
{
  __shared__ unsigned short k_lds[128 * 64];
  __shared__ unsigned short vt[32 * 128];
  __shared__ unsigned short p_lds[32 * 128];
  __shared__ unsigned short q_lds[32 * 64];
  __shared__ unsigned short bias_lds[32 * 136];
  __shared__ float mxlds[4][32];
  __shared__ float smlds[4][32];
  const int tid = threadIdx.x;
  const int h = blockIdx.x & 3, b = blockIdx.x >> 2;
  const int j0 = b * 32 - 48;
  const int l = tid & 63, wv = tid >> 6;
  const int lm = l & 15, kg = l >> 4;

  { // Q stage
    const int r = tid >> 3, c0 = (tid & 7) << 2;
    ushort4 v = *(const ushort4*)(q_b + (size_t)(b * 32 + r) * 128 + h * 32 + c0);
    *(ushort4*)&q_lds[r * 64 + (c0 ^ ((r & 7) << 3))] = v;
  }
  { // bias stage
    const int r = tid >> 3, c0 = (tid & 7) << 4;
    const uint4* g = (const uint4*)(bias_h + (size_t)h * (NTOK * 128) + (size_t)(b * 32 + r) * 128 + c0);
    uint4 v0 = g[0], v1 = g[1];
    *(uint4*)&bias_lds[r * 136 + c0] = v0;
    *(uint4*)&bias_lds[r * 136 + c0 + 8] = v1;
  }
  { // K stage
    const int jw = tid >> 1, cb = (tid & 1) << 4;
    const int j = j0 + jw;
    uint4 kv0 = {0,0,0,0}, kv1 = {0,0,0,0};
    if (j >= 0 && j < NTOK) {
      const uint4* gk = (const uint4*)(k_b + (size_t)j * 128 + h * 32 + cb);
      kv0 = gk[0]; kv1 = gk[1];
    }
    const int xk = (jw & 7) << 3;
    *(uint4*)&k_lds[jw * 64 + (cb ^ xk)] = kv0;
    *(uint4*)&k_lds[jw * 64 + ((cb + 8) ^ xk)] = kv1;
  }
  { // V stage from vt_b
    const int c = tid >> 3, koff = (tid & 7) << 4;
    const int j = j0 + koff;
    uint4 v0 = {0,0,0,0}, v1 = {0,0,0,0};
    if (j >= 0 && j + 15 < NTOK) {
      const uint4* gv = (const uint4*)(vt_b + (size_t)(h * 32 + c) * NTOK + j);
      v0 = gv[0]; v1 = gv[1];
    }
    const int xc = (c & 7) << 3;
    *(uint4*)&vt[c * 128 + (koff ^ xc)] = v0;
    *(uint4*)&vt[c * 128 + ((koff + 8) ^ xc)] = v1;
  }
  __syncthreads();

  // QK^T
  f32x4 sc[2][2] = {};
  {
    const int xa = (lm & 7) << 3;
    short8_t aq[2], bk[2];
#pragma unroll
    for (int mi = 0; mi < 2; ++mi)
      aq[mi] = *(const short8_t*)&q_lds[(mi * 16 + lm) * 64 + ((kg * 8) ^ xa)];
#pragma unroll
    for (int ni = 0; ni < 2; ++ni) {
      const int key = (wv * 2 + ni) * 16 + lm;
      bk[ni] = *(const short8_t*)&k_lds[key * 64 + ((kg * 8) ^ ((key & 7) << 3))];
    }
#pragma unroll
    for (int mi = 0; mi < 2; ++mi)
#pragma unroll
      for (int ni = 0; ni < 2; ++ni)
        sc[mi][ni] = __builtin_amdgcn_mfma_f32_16x16x32_bf16(aq[mi], bk[ni], sc[mi][ni], 0, 0, 0);
  }
  float sv[2][2][4];
#pragma unroll
  for (int mi = 0; mi < 2; ++mi)
#pragma unroll
    for (int ni = 0; ni < 2; ++ni)
#pragma unroll
      for (int r = 0; r < 4; ++r) {
        const int q = mi * 16 + kg * 4 + r;
        const int key = (wv * 2 + ni) * 16 + lm;
        sv[mi][ni][r] = sc[mi][ni][r] + bu2f(bias_lds[q * 136 + key]);
      }
#pragma unroll
  for (int mi = 0; mi < 2; ++mi)
#pragma unroll
    for (int r = 0; r < 4; ++r) {
      float m0 = fmaxf(sv[mi][0][r], sv[mi][1][r]);
#pragma unroll
      for (int msk = 1; msk < 16; msk <<= 1) m0 = fmaxf(m0, __shfl_xor(m0, msk));
      if (lm == 0) mxlds[wv][mi * 16 + kg * 4 + r] = m0;
    }
  __syncthreads();
#pragma unroll
  for (int mi = 0; mi < 2; ++mi)
#pragma unroll
    for (int r = 0; r < 4; ++r) {
      const int q = mi * 16 + kg * 4 + r;
      const float m = fmaxf(fmaxf(mxlds[0][q], mxlds[1][q]), fmaxf(mxlds[2][q], mxlds[3][q]));
      float s = 0.f;
#pragma unroll
      for (int ni = 0; ni < 2; ++ni) {
        const float e = __expf(sv[mi][ni][r] - m);
        const int key = (wv * 2 + ni) * 16 + lm;
        p_lds[q * 128 + ((key & 7) | ((key & 120) ^ ((q & 7) << 3)))] = f2bu(e);
        s += e;
      }
#pragma unroll
      for (int msk = 1; msk < 16; msk <<= 1) s += __shfl_xor(s, msk);
      if (lm == 0) smlds[wv][q] = s;
    }
  __syncthreads();   // all waves' P and sums visible

  // PV: wave (wv) -> rows rh=(wv&1)*16, cols ch=(wv>>1)*16, keys 0..127
  {
    const int rh = (wv & 1) << 4, ch = (wv >> 1) << 4;
    const int rowl = rh + lm;
    const int coll = ch + lm;
    const int xr = (rowl & 7) << 3, xc = (coll & 7) << 3;
    f32x4 acc = {};
#pragma unroll
    for (int ks = 0; ks < 4; ++ks) {
      const int ko = ks * 32 + kg * 8;
      short8_t pa = *(const short8_t*)&p_lds[rowl * 128 + (ko ^ xr)];
      short8_t vb = *(const short8_t*)&vt[coll * 128 + (ko ^ xc)];
      acc = __builtin_amdgcn_mfma_f32_16x16x32_bf16(pa, vb, acc, 0, 0, 0);
    }
#pragma unroll
    for (int r = 0; r < 4; ++r) {
      const int row = rh + kg * 4 + r;
      const int col = ch + lm;
      const float tot = smlds[0][row] + smlds[1][row] + smlds[2][row] + smlds[3][row];
      const float inv = 1.f / tot;
      const float gsv = bu2f(gsig_b[(size_t)(b * 32 + row) * 128 + h * 32 + col]);
      o_b[(size_t)(b * 32 + row) * 128 + h * 32 + col] = f2bu(acc[r] * inv * gsv);
    }
  }
}

// ------------------------------------------------------------------
// N3: out = gs * (o @ Wo), direct-f32 Wo fragments. 128 blocks x 16 rows.
// ------------------------------------------------------------------
__global__ __launch_bounds__(256) void out_kernel(
    const float* __restrict__ Wo, const unsigned short* __restrict__ o_b,
    const unsigned short* __restrict__ gs_b, float* __restrict__ out)
{
  __shared__ unsigned short a_lds[16 * 128];
  const int tid = threadIdx.x;
  const int row0 = blockIdx.x * 16;
  const int l = tid & 63, wv = tid >> 6;
  const int lm = l & 15, kg = l >> 4;
  {
    const int r = tid >> 4, c0 = (tid & 15) << 3;
    uint4 v = *(const uint4*)(o_b + (size_t)(row0 + r) * 128 + c0);
    *(uint4*)&a_lds[r * 128 + (c0 ^ ((r & 7) << 3))] = v;
  }
  __syncthreads();
  f32x4 acc[2] = {};
  const int xa = (lm & 7) << 3;
#pragma unroll
  for (int ks = 0; ks < 4; ++ks) {
    const int ko = ks * 32 + kg * 8;
    short8_t av = *(const short8_t*)&a_lds[lm * 128 + (ko ^ xa)];
#pragma unroll
    for (int ni = 0; ni < 2; ++ni) {
      short8_t bv = wfrag(Wo, nullptr, ko, (wv * 2 + ni) * 16 + lm);
      acc[ni] = __builtin_amdgcn_mfma_f32_16x16x32_bf16(av, bv, acc[ni], 0, 0, 0);
    }
  }
#pragma unroll
  for (int ni = 0; ni < 2; ++ni)
#pragma unroll
    for (int r = 0; r < 4; ++r) {
      const int rl = kg * 4 + r;
      const int n = (wv * 2 + ni) * 16 + lm;
      const float gsv = bu2f(gs_b[(size_t)(row0 + rl) * 128 + n]);
      out[(size_t)(row0 + rl) * 128 + n] = acc[ni][r] * gsv;
    }
}

extern "C" void kernel_launch(void* const* d_in, const int* in_sizes, int n_in,
                              void* d_out, int out_size, void* d_ws, size_t ws_size,
                              hipStream_t stream) {
  const float* act     = (const float*)d_in[0];
  const float* pair    = (const float*)d_in[1];
  const float* cond    = (const float*)d_in[2];
  const float* lns_q   = (const float*)d_in[4];
  const float* Wgate_q = (const float*)d_in[5];
  const float* bgate_q = (const float*)d_in[6];
  const float* Wskip_q = (const float*)d_in[7];
  const float* lns_k   = (const float*)d_in[8];
  const float* Wgate_k = (const float*)d_in[9];
  const float* bgate_k = (const float*)d_in[10];
  const float* Wskip_k = (const float*)d_in[11];
  const float* lnz_w   = (const float*)d_in[12];
  const float* Wq      = (const float*)d_in[13];
  const float* bq      = (const float*)d_in[14];
  const float* Wk      = (const float*)d_in[15];
  const float* Wv      = (const float*)d_in[16];
  const float* Wg      = (const float*)d_in[17];
  const float* Wb      = (const float*)d_in[18];
  const float* Wo      = (const float*)d_in[19];
  const float* Wgs     = (const float*)d_in[20];
  const float* bgs     = (const float*)d_in[21];
  float* out           = (float*)d_out;

  unsigned short* ws = (unsigned short*)d_ws;
  unsigned short* q_b    = ws;
  unsigned short* k_b    = ws + 262144;
  unsigned short* vt_b   = ws + 524288;             // [128 dims][2048 tokens]
  unsigned short* gsig_b = ws + 786432;
  unsigned short* gs_b   = ws + 1048576;
  unsigned short* o_b    = ws + 1310720;
  unsigned short* bias_h = ws + 1572864;            // 4*2048*128

  hipLaunchKernelGGL(bias_proj_kernel, dim3(1344), dim3(256), 0, stream,
                     act, cond, lns_q, lns_k,
                     Wgate_q, Wskip_q, Wgate_k, Wskip_k,
                     Wq, Wk, Wv, Wg, Wgs,
                     bgate_q, bgate_k, bq, bgs,
                     pair, lnz_w, Wb,
                     q_b, k_b, vt_b, gsig_b, gs_b, bias_h);
  hipLaunchKernelGGL(attn_kernel, dim3(256), dim3(256), 0, stream,
                     q_b, k_b, vt_b, gsig_b, bias_h, o_b);
  hipLaunchKernelGGL(out_kernel, dim3(128), dim3(256), 0, stream,
                     Wo, o_b, gs_b, out);
}

// Round 18
// 25.450 us; speedup vs baseline: 30.3709x; 1.0098x over previous
//
#include <hip/hip_runtime.h>
#include <hip/hip_bf16.h>

#define NTOK 2048

typedef __attribute__((ext_vector_type(8))) short short8_t;
typedef __attribute__((ext_vector_type(4))) float f32x4;

__device__ __forceinline__ float bu2f(unsigned short u) {
  unsigned int x = ((unsigned int)u) << 16; float f; __builtin_memcpy(&f, &x, 4); return f;
}
__device__ __forceinline__ unsigned short f2bu(float f) {
  __hip_bfloat16 h = __float2bfloat16(f);
  unsigned short u; __builtin_memcpy(&u, &h, 2); return u;
}
__device__ __forceinline__ float sigm(float x) { return 1.0f / (1.0f + __expf(-x)); }
__device__ __forceinline__ uint4 pack8(const float* v) {
  unsigned short u[8];
#pragma unroll
  for (int i = 0; i < 8; ++i) u[i] = f2bu(v[i]);
  uint4 r; __builtin_memcpy(&r, u, 16); return r;
}
__device__ __forceinline__ short8_t pk8s(const float* v) {
  unsigned short u[8];
#pragma unroll
  for (int i = 0; i < 8; ++i) u[i] = f2bu(v[i]);
  short8_t r; __builtin_memcpy(&r, u, 16); return r;
}

__device__ __forceinline__ short8_t wfrag(const float* __restrict__ W,
                                          const float* __restrict__ lns,
                                          int ko, int n) {
  float v[8];
#pragma unroll
  for (int i = 0; i < 8; ++i) v[i] = W[(size_t)(ko + i) * 128 + n];
  if (lns) {
    float4 l0 = *(const float4*)(lns + ko);
    float4 l1 = *(const float4*)(lns + ko + 4);
    v[0] *= l0.x; v[1] *= l0.y; v[2] *= l0.z; v[3] *= l0.w;
    v[4] *= l1.x; v[5] *= l1.y; v[6] *= l1.z; v[7] *= l1.w;
  }
  return pk8s(v);
}

__device__ __forceinline__ void gemm_dw(const unsigned short* a_lds,
                                        const float* __restrict__ W,
                                        const float* __restrict__ lns,
                                        int lm, int kg, int wv, f32x4 acc[2][2]) {
  const int xa = (lm & 7) << 3;
#pragma unroll
  for (int ks = 0; ks < 4; ++ks) {
    const int ko = ks * 32 + kg * 8;
    short8_t av[2], bv[2];
#pragma unroll
    for (int mi = 0; mi < 2; ++mi)
      av[mi] = *(const short8_t*)&a_lds[(mi * 16 + lm) * 128 + (ko ^ xa)];
#pragma unroll
    for (int ni = 0; ni < 2; ++ni)
      bv[ni] = wfrag(W, lns, ko, (wv * 2 + ni) * 16 + lm);
#pragma unroll
    for (int mi = 0; mi < 2; ++mi)
#pragma unroll
      for (int ni = 0; ni < 2; ++ni)
        acc[mi][ni] = __builtin_amdgcn_mfma_f32_16x16x32_bf16(av[mi], bv[ni], acc[mi][ni], 0, 0, 0);
  }
}

// ------------------------------------------------------------------
// N1: blocks [0,320) = self-contained projections (FIRST);
//     blocks [320,576) = windowed pair bias, 4 cells/thread (strided by 256
//     inside the block so lanes stay coalesced). 576 blocks total -> whole
//     grid resident in ONE scheduling round (<=3 blocks/CU at VGPR~144).
// ------------------------------------------------------------------
__global__ __launch_bounds__(256) void bias_proj_kernel(
    const float* __restrict__ act, const float* __restrict__ cond,
    const float* __restrict__ lns_q, const float* __restrict__ lns_k,
    const float* __restrict__ WgQ, const float* __restrict__ WsQ,
    const float* __restrict__ WgK, const float* __restrict__ WsK,
    const float* __restrict__ Wq, const float* __restrict__ Wk,
    const float* __restrict__ Wv, const float* __restrict__ Wg,
    const float* __restrict__ Wgs,
    const float* __restrict__ bgate_q, const float* __restrict__ bgate_k,
    const float* __restrict__ bq, const float* __restrict__ bgs,
    const float* __restrict__ pair, const float* __restrict__ lnz_w,
    const float* __restrict__ Wb,
    unsigned short* __restrict__ q_b, unsigned short* __restrict__ k_b,
    unsigned short* __restrict__ vt_b, unsigned short* __restrict__ gsig_b,
    unsigned short* __restrict__ gs_b, unsigned short* __restrict__ bias_h)
{
  __shared__ unsigned short a_lds[32 * 128];
  __shared__ unsigned short xn_lds[32 * 136];
  __shared__ unsigned short a2_lds[32 * 128];
  __shared__ float lw[16];
  __shared__ float wbz[16][4];
  const int tid = threadIdx.x;
  const int bid = blockIdx.x;

  if (bid >= 320) {
    // ---- windowed pair bias: 4 cells per thread ----
    if (tid < 16) lw[tid] = lnz_w[tid];
    if (tid < 64) wbz[tid >> 2][tid & 3] = Wb[tid];
    __syncthreads();
    const int base = (bid - 320) * 1024;
#pragma unroll
    for (int s = 0; s < 4; ++s) {
      const int idx = base + s * 256 + tid;
      const int i = idx >> 7, jw = idx & 127;
      const int j = ((i >> 5) << 5) - 48 + jw;
      float bo[4] = {-1e9f, -1e9f, -1e9f, -1e9f};
      if (j >= 0 && j < NTOK) {
        const float4* p = (const float4*)(pair + ((size_t)i * NTOK + j) * 16);
        float4 z0 = p[0], z1 = p[1], z2 = p[2], z3 = p[3];
        float z[16] = {z0.x, z0.y, z0.z, z0.w, z1.x, z1.y, z1.z, z1.w,
                       z2.x, z2.y, z2.z, z2.w, z3.x, z3.y, z3.z, z3.w};
        float s1 = 0.f, ss = 0.f;
#pragma unroll
        for (int c = 0; c < 16; ++c) { s1 += z[c]; ss += z[c]*z[c]; }
        const float m = s1 * (1.f/16.f), v = ss * (1.f/16.f) - m*m;
        const float r = rsqrtf(v + 1e-5f);
        bo[0] = bo[1] = bo[2] = bo[3] = 0.f;
#pragma unroll
        for (int c = 0; c < 16; ++c) {
          const float zn = (z[c] - m) * r * lw[c];
          bo[0] += zn * wbz[c][0]; bo[1] += zn * wbz[c][1];
          bo[2] += zn * wbz[c][2]; bo[3] += zn * wbz[c][3];
        }
      }
#pragma unroll
      for (int h = 0; h < 4; ++h)
        bias_h[(size_t)h * (NTOK * 128) + idx] = f2bu(bo[h]);
    }
    return;
  }

  // ---- self-contained projection ----
  const int br = bid / 64;       // 0:q 1:g 2:k 3:v 4:gs
  const int rt = bid % 64;
  const int row0 = rt * 32;
  const int l = tid & 63, wv = tid >> 6;
  const int lm = l & 15, kg = l >> 4;

  { // LN stage
    const int r = tid >> 3;
    const int c0 = (tid & 7) << 4;
    float xv[16], cv[16];
    const float4* ap = (const float4*)(act + (size_t)(row0 + r) * 128 + c0);
    const float4* cp = (const float4*)(cond + (size_t)(row0 + r) * 128 + c0);
#pragma unroll
    for (int i = 0; i < 4; ++i) {
      float4 a4 = ap[i], b4 = cp[i];
      xv[4*i+0]=a4.x; xv[4*i+1]=a4.y; xv[4*i+2]=a4.z; xv[4*i+3]=a4.w;
      cv[4*i+0]=b4.x; cv[4*i+1]=b4.y; cv[4*i+2]=b4.z; cv[4*i+3]=b4.w;
    }
    float sx=0.f, sxx=0.f, sc=0.f, scc=0.f;
#pragma unroll
    for (int i = 0; i < 16; ++i) { sx+=xv[i]; sxx+=xv[i]*xv[i]; sc+=cv[i]; scc+=cv[i]*cv[i]; }
#pragma unroll
    for (int m = 1; m < 8; m <<= 1) {
      sx += __shfl_xor(sx, m); sxx += __shfl_xor(sxx, m);
      sc += __shfl_xor(sc, m); scc += __shfl_xor(scc, m);
    }
    const float mx = sx * (1.f/128.f), vx = sxx*(1.f/128.f) - mx*mx;
    const float mc = sc * (1.f/128.f), vc = scc*(1.f/128.f) - mc*mc;
    const float rx = rsqrtf(vx + 1e-5f), rc = rsqrtf(vc + 1e-5f);
    float xo[16], so[16];
#pragma unroll
    for (int i = 0; i < 16; ++i) { xo[i] = (xv[i]-mx)*rx; so[i] = (cv[i]-mc)*rc; }
    const int x = (r & 7) << 3;
    if (br == 4) {
      *(uint4*)&a_lds[r * 128 + (c0 ^ x)] = pack8(cv);
      *(uint4*)&a_lds[r * 128 + ((c0 + 8) ^ x)] = pack8(cv + 8);
    } else {
      *(uint4*)&a_lds[r * 128 + (c0 ^ x)] = pack8(so);
      *(uint4*)&a_lds[r * 128 + ((c0 + 8) ^ x)] = pack8(so + 8);
      *(uint4*)&xn_lds[r * 136 + c0] = pack8(xo);
      *(uint4*)&xn_lds[r * 136 + c0 + 8] = pack8(xo + 8);
    }
  }
  __syncthreads();

  if (br == 4) {
    f32x4 acc[2][2] = {};
    gemm_dw(a_lds, Wgs, nullptr, lm, kg, wv, acc);
    float bgv[2];
#pragma unroll
    for (int ni = 0; ni < 2; ++ni) bgv[ni] = bgs[(wv * 2 + ni) * 16 + lm];
#pragma unroll
    for (int mi = 0; mi < 2; ++mi)
#pragma unroll
      for (int ni = 0; ni < 2; ++ni)
#pragma unroll
        for (int r = 0; r < 4; ++r) {
          const int rl = mi * 16 + kg * 4 + r;
          const int n = (wv * 2 + ni) * 16 + lm;
          gs_b[(size_t)(row0 + rl) * 128 + n] = f2bu(sigm(acc[mi][ni][r] + bgv[ni]));
        }
    return;
  }

  const bool useq = (br < 2);
  const float* Wgt = useq ? WgQ : WgK;
  const float* Wsk = useq ? WsQ : WsK;
  const float* lns = useq ? lns_q : lns_k;
  const float* bg  = useq ? bgate_q : bgate_k;

  f32x4 ag[2][2] = {}, as2[2][2] = {};
  gemm_dw(a_lds, Wgt, lns, lm, kg, wv, ag);
  gemm_dw(a_lds, Wsk, lns, lm, kg, wv, as2);
  { // combine: a = sigm(gate+bg)*xn + skip -> a2 (swizzled bf16)
    float bgv[2];
#pragma unroll
    for (int ni = 0; ni < 2; ++ni) bgv[ni] = bg[(wv * 2 + ni) * 16 + lm];
#pragma unroll
    for (int mi = 0; mi < 2; ++mi)
#pragma unroll
      for (int ni = 0; ni < 2; ++ni)
#pragma unroll
        for (int r = 0; r < 4; ++r) {
          const int rl = mi * 16 + kg * 4 + r;
          const int n = (wv * 2 + ni) * 16 + lm;
          const float gate = sigm(ag[mi][ni][r] + bgv[ni]);
          const float a = gate * bu2f(xn_lds[rl * 136 + n]) + as2[mi][ni][r];
          a2_lds[rl * 128 + (n ^ ((rl & 7) << 3))] = f2bu(a);
        }
  }
  __syncthreads();

  const float* Wout = (br == 0) ? Wq : (br == 1) ? Wg : (br == 2) ? Wk : Wv;
  f32x4 ao[2][2] = {};
  gemm_dw(a2_lds, Wout, nullptr, lm, kg, wv, ao);

  if (br == 3) {
#pragma unroll
    for (int mi = 0; mi < 2; ++mi)
#pragma unroll
      for (int ni = 0; ni < 2; ++ni) {
        const int n = (wv * 2 + ni) * 16 + lm;
        const int tok0 = row0 + mi * 16 + kg * 4;
        ushort4 o;
        o.x = f2bu(ao[mi][ni][0]); o.y = f2bu(ao[mi][ni][1]);
        o.z = f2bu(ao[mi][ni][2]); o.w = f2bu(ao[mi][ni][3]);
        *(ushort4*)(vt_b + (size_t)n * NTOK + tok0) = o;
      }
    return;
  }
  const float scale = 0.17677669529663687f;
  float bqv[2] = {0.f, 0.f};
  if (br == 0) {
#pragma unroll
    for (int ni = 0; ni < 2; ++ni) bqv[ni] = bq[(wv * 2 + ni) * 16 + lm];
  }
  unsigned short* dst = (br == 0) ? q_b : (br == 1) ? gsig_b : k_b;
#pragma unroll
  for (int mi = 0; mi < 2; ++mi)
#pragma unroll
    for (int ni = 0; ni < 2; ++ni)
#pragma unroll
      for (int r = 0; r < 4; ++r) {
        const int rl = mi * 16 + kg * 4 + r;
        const int n = (wv * 2 + ni) * 16 + lm;
        float v = ao[mi][ni][r];
        if (br == 0) v = (v + bqv[ni]) * scale;
        else if (br == 1) v = sigm(v);
        dst[(size_t)(row0 + rl) * 128 + n] = f2bu(v);
      }
}

// ------------------------------------------------------------------
// N2 (r17 verbatim): attention per (qblock, head). Row/col-split PV.
// ------------------------------------------------------------------
__global__ __launch_bounds__(256) void attn_kernel(
    const unsigned short* __restrict__ q_b, const unsigned short* __restrict__ k_b,
    const unsigned short* __restrict__ vt_b, const unsigned short* __restrict__ gsig_b,
    const unsigned short* __restrict__ bias_h, unsigned short* __restrict__ o_b)
{
  __shared__ unsigned short k_lds[128 * 64];
  __shared__ unsigned short vt[32 * 128];
  __shared__ unsigned short p_lds[32 * 128];
  __shared__ unsigned short q_lds[32 * 64];
  __shared__ unsigned short bias_lds[32 * 136];
  __shared__ float mxlds[4][32];
  __shared__ float smlds[4][32];
  const int tid = threadIdx.x;
  const int h = blockIdx.x & 3, b = blockIdx.x >> 2;
  const int j0 = b * 32 - 48;
  const int l = tid & 63, wv = tid >> 6;
  const int lm = l & 15, kg = l >> 4;

  { // Q stage
    const int r = tid >> 3, c0 = (tid & 7) << 2;
    ushort4 v = *(const ushort4*)(q_b + (size_t)(b * 32 + r) * 128 + h * 32 + c0);
    *(ushort4*)&q_lds[r * 64 + (c0 ^ ((r & 7) << 3))] = v;
  }
  { // bias stage
    const int r = tid >> 3, c0 = (tid & 7) << 4;
    const uint4* g = (const uint4*)(bias_h + (size_t)h * (NTOK * 128) + (size_t)(b * 32 + r) * 128 + c0);
    uint4 v0 = g[0], v1 = g[1];
    *(uint4*)&bias_lds[r * 136 + c0] = v0;
    *(uint4*)&bias_lds[r * 136 + c0 + 8] = v1;
  }
  { // K stage
    const int jw = tid >> 1, cb = (tid & 1) << 4;
    const int j = j0 + jw;
    uint4 kv0 = {0,0,0,0}, kv1 = {0,0,0,0};
    if (j >= 0 && j < NTOK) {
      const uint4* gk = (const uint4*)(k_b + (size_t)j * 128 + h * 32 + cb);
      kv0 = gk[0]; kv1 = gk[1];
    }
    const int xk = (jw & 7) << 3;
    *(uint4*)&k_lds[jw * 64 + (cb ^ xk)] = kv0;
    *(uint4*)&k_lds[jw * 64 + ((cb + 8) ^ xk)] = kv1;
  }
  { // V stage from vt_b
    const int c = tid >> 3, koff = (tid & 7) << 4;
    const int j = j0 + koff;
    uint4 v0 = {0,0,0,0}, v1 = {0,0,0,0};
    if (j >= 0 && j + 15 < NTOK) {
      const uint4* gv = (const uint4*)(vt_b + (size_t)(h * 32 + c) * NTOK + j);
      v0 = gv[0]; v1 = gv[1];
    }
    const int xc = (c & 7) << 3;
    *(uint4*)&vt[c * 128 + (koff ^ xc)] = v0;
    *(uint4*)&vt[c * 128 + ((koff + 8) ^ xc)] = v1;
  }
  __syncthreads();

  // QK^T
  f32x4 sc[2][2] = {};
  {
    const int xa = (lm & 7) << 3;
    short8_t aq[2], bk[2];
#pragma unroll
    for (int mi = 0; mi < 2; ++mi)
      aq[mi] = *(const short8_t*)&q_lds[(mi * 16 + lm) * 64 + ((kg * 8) ^ xa)];
#pragma unroll
    for (int ni = 0; ni < 2; ++ni) {
      const int key = (wv * 2 + ni) * 16 + lm;
      bk[ni] = *(const short8_t*)&k_lds[key * 64 + ((kg * 8) ^ ((key & 7) << 3))];
    }
#pragma unroll
    for (int mi = 0; mi < 2; ++mi)
#pragma unroll
      for (int ni = 0; ni < 2; ++ni)
        sc[mi][ni] = __builtin_amdgcn_mfma_f32_16x16x32_bf16(aq[mi], bk[ni], sc[mi][ni], 0, 0, 0);
  }
  float sv[2][2][4];
#pragma unroll
  for (int mi = 0; mi < 2; ++mi)
#pragma unroll
    for (int ni = 0; ni < 2; ++ni)
#pragma unroll
      for (int r = 0; r < 4; ++r) {
        const int q = mi * 16 + kg * 4 + r;
        const int key = (wv * 2 + ni) * 16 + lm;
        sv[mi][ni][r] = sc[mi][ni][r] + bu2f(bias_lds[q * 136 + key]);
      }
#pragma unroll
  for (int mi = 0; mi < 2; ++mi)
#pragma unroll
    for (int r = 0; r < 4; ++r) {
      float m0 = fmaxf(sv[mi][0][r], sv[mi][1][r]);
#pragma unroll
      for (int msk = 1; msk < 16; msk <<= 1) m0 = fmaxf(m0, __shfl_xor(m0, msk));
      if (lm == 0) mxlds[wv][mi * 16 + kg * 4 + r] = m0;
    }
  __syncthreads();
#pragma unroll
  for (int mi = 0; mi < 2; ++mi)
#pragma unroll
    for (int r = 0; r < 4; ++r) {
      const int q = mi * 16 + kg * 4 + r;
      const float m = fmaxf(fmaxf(mxlds[0][q], mxlds[1][q]), fmaxf(mxlds[2][q], mxlds[3][q]));
      float s = 0.f;
#pragma unroll
      for (int ni = 0; ni < 2; ++ni) {
        const float e = __expf(sv[mi][ni][r] - m);
        const int key = (wv * 2 + ni) * 16 + lm;
        p_lds[q * 128 + ((key & 7) | ((key & 120) ^ ((q & 7) << 3)))] = f2bu(e);
        s += e;
      }
#pragma unroll
      for (int msk = 1; msk < 16; msk <<= 1) s += __shfl_xor(s, msk);
      if (lm == 0) smlds[wv][q] = s;
    }
  __syncthreads();   // all waves' P and sums visible

  // PV: wave (wv) -> rows rh=(wv&1)*16, cols ch=(wv>>1)*16, keys 0..127
  {
    const int rh = (wv & 1) << 4, ch = (wv >> 1) << 4;
    const int rowl = rh + lm;
    const int coll = ch + lm;
    const int xr = (rowl & 7) << 3, xc = (coll & 7) << 3;
    f32x4 acc = {};
#pragma unroll
    for (int ks = 0; ks < 4; ++ks) {
      const int ko = ks * 32 + kg * 8;
      short8_t pa = *(const short8_t*)&p_lds[rowl * 128 + (ko ^ xr)];
      short8_t vb = *(const short8_t*)&vt[coll * 128 + (ko ^ xc)];
      acc = __builtin_amdgcn_mfma_f32_16x16x32_bf16(pa, vb, acc, 0, 0, 0);
    }
#pragma unroll
    for (int r = 0; r < 4; ++r) {
      const int row = rh + kg * 4 + r;
      const int col = ch + lm;
      const float tot = smlds[0][row] + smlds[1][row] + smlds[2][row] + smlds[3][row];
      const float inv = 1.f / tot;
      const float gsv = bu2f(gsig_b[(size_t)(b * 32 + row) * 128 + h * 32 + col]);
      o_b[(size_t)(b * 32 + row) * 128 + h * 32 + col] = f2bu(acc[r] * inv * gsv);
    }
  }
}

// ------------------------------------------------------------------
// N3: out = gs * (o @ Wo), direct-f32 Wo fragments. 128 blocks x 16 rows.
// ------------------------------------------------------------------
__global__ __launch_bounds__(256) void out_kernel(
    const float* __restrict__ Wo, const unsigned short* __restrict__ o_b,
    const unsigned short* __restrict__ gs_b, float* __restrict__ out)
{
  __shared__ unsigned short a_lds[16 * 128];
  const int tid = threadIdx.x;
  const int row0 = blockIdx.x * 16;
  const int l = tid & 63, wv = tid >> 6;
  const int lm = l & 15, kg = l >> 4;
  {
    const int r = tid >> 4, c0 = (tid & 15) << 3;
    uint4 v = *(const uint4*)(o_b + (size_t)(row0 + r) * 128 + c0);
    *(uint4*)&a_lds[r * 128 + (c0 ^ ((r & 7) << 3))] = v;
  }
  __syncthreads();
  f32x4 acc[2] = {};
  const int xa = (lm & 7) << 3;
#pragma unroll
  for (int ks = 0; ks < 4; ++ks) {
    const int ko = ks * 32 + kg * 8;
    short8_t av = *(const short8_t*)&a_lds[lm * 128 + (ko ^ xa)];
#pragma unroll
    for (int ni = 0; ni < 2; ++ni) {
      short8_t bv = wfrag(Wo, nullptr, ko, (wv * 2 + ni) * 16 + lm);
      acc[ni] = __builtin_amdgcn_mfma_f32_16x16x32_bf16(av, bv, acc[ni], 0, 0, 0);
    }
  }
#pragma unroll
  for (int ni = 0; ni < 2; ++ni)
#pragma unroll
    for (int r = 0; r < 4; ++r) {
      const int rl = kg * 4 + r;
      const int n = (wv * 2 + ni) * 16 + lm;
      const float gsv = bu2f(gs_b[(size_t)(row0 + rl) * 128 + n]);
      out[(size_t)(row0 + rl) * 128 + n] = acc[ni][r] * gsv;
    }
}

extern "C" void kernel_launch(void* const* d_in, const int* in_sizes, int n_in,
                              void* d_out, int out_size, void* d_ws, size_t ws_size,
                              hipStream_t stream) {
  const float* act     = (const float*)d_in[0];
  const float* pair    = (const float*)d_in[1];
  const float* cond    = (const float*)d_in[2];
  const float* lns_q   = (const float*)d_in[4];
  const float* Wgate_q = (const float*)d_in[5];
  const float* bgate_q = (const float*)d_in[6];
  const float* Wskip_q = (const float*)d_in[7];
  const float* lns_k   = (const float*)d_in[8];
  const float* Wgate_k = (const float*)d_in[9];
  const float* bgate_k = (const float*)d_in[10];
  const float* Wskip_k = (const float*)d_in[11];
  const float* lnz_w   = (const float*)d_in[12];
  const float* Wq      = (const float*)d_in[13];
  const float* bq      = (const float*)d_in[14];
  const float* Wk      = (const float*)d_in[15];
  const float* Wv      = (const float*)d_in[16];
  const float* Wg      = (const float*)d_in[17];
  const float* Wb      = (const float*)d_in[18];
  const float* Wo      = (const float*)d_in[19];
  const float* Wgs     = (const float*)d_in[20];
  const float* bgs     = (const float*)d_in[21];
  float* out           = (float*)d_out;

  unsigned short* ws = (unsigned short*)d_ws;
  unsigned short* q_b    = ws;
  unsigned short* k_b    = ws + 262144;
  unsigned short* vt_b   = ws + 524288;             // [128 dims][2048 tokens]
  unsigned short* gsig_b = ws + 786432;
  unsigned short* gs_b   = ws + 1048576;
  unsigned short* o_b    = ws + 1310720;
  unsigned short* bias_h = ws + 1572864;            // 4*2048*128

  hipLaunchKernelGGL(bias_proj_kernel, dim3(576), dim3(256), 0, stream,
                     act, cond, lns_q, lns_k,
                     Wgate_q, Wskip_q, Wgate_k, Wskip_k,
                     Wq, Wk, Wv, Wg, Wgs,
                     bgate_q, bgate_k, bq, bgs,
                     pair, lnz_w, Wb,
                     q_b, k_b, vt_b, gsig_b, gs_b, bias_h);
  hipLaunchKernelGGL(attn_kernel, dim3(256), dim3(256), 0, stream,
                     q_b, k_b, vt_b, gsig_b, bias_h, o_b);
  hipLaunchKernelGGL(out_kernel, dim3(128), dim3(256), 0, stream,
                     Wo, o_b, gs_b, out);
}